// Round 1
// baseline (2259.905 us; speedup 1.0000x reference)
//
#include <hip/hip_runtime.h>
#include <math.h>

// ---------------- problem constants ----------------
#define D_MODEL 768
#define D_STATE 16
#define DT_RANK 48
#define D_INNER 1536           // 2*D_MODEL
#define XZ_DIM  3072           // 2*D_INNER
#define PROJ_DIM 80            // DT_RANK + 2*D_STATE
#define Bb 2
#define Ll 1024
#define ROWS (Bb*Ll)           // 2048

// ---------------- ws layout (float offsets) ----------------
#define OFF_PART   0u                     // 4 matrices x 64 partials
#define OFF_SW     256u                   // 4 scalars
#define OFF_WQIN   512u                   // 3072x768
#define OFF_WQXPT  (OFF_WQIN  + 2359296u) // 1536x80 (transposed)
#define OFF_WQDT   (OFF_WQXPT + 122880u)  // 1536x48
#define OFF_WQOUT  (OFF_WQDT  + 73728u)   // 768x1536
#define OFF_XQ1    (OFF_WQOUT + 1179648u) // 2048x768
#define OFF_S1     (OFF_XQ1   + 1572864u) // 2048
#define OFF_XZ     (OFF_S1    + 2048u)    // 2048x3072
#define OFF_XS     (OFF_XZ    + 6291456u) // 2048x1536
#define OFF_XQ2    (OFF_XS    + 3145728u) // 2048x1536
#define OFF_S2     (OFF_XQ2   + 3145728u) // 2048
#define OFF_PROJ   (OFF_S2    + 2048u)    // 2048x80
#define OFF_XQ3    (OFF_PROJ  + 163840u)  // 2048x48
#define OFF_S3     (OFF_XQ3   + 98304u)   // 2048
#define OFF_DMOD   (OFF_S3    + 2048u)    // 2048x1536
#define OFF_YG     (OFF_DMOD  + 3145728u) // 2048x1536
#define OFF_XQ4    (OFF_YG    + 3145728u) // 2048x1536
#define OFF_S4     (OFF_XQ4   + 3145728u) // 2048

// ---------------- helpers ----------------
__device__ __forceinline__ float blk_sum(float v, float* sm) {
    int tid = threadIdx.x;
    #pragma unroll
    for (int off = 32; off; off >>= 1) v += __shfl_down(v, off);
    __syncthreads();
    if ((tid & 63) == 0) sm[tid >> 6] = v;
    __syncthreads();
    return (sm[0] + sm[1]) + (sm[2] + sm[3]);
}
__device__ __forceinline__ float blk_max(float v, float* sm) {
    int tid = threadIdx.x;
    #pragma unroll
    for (int off = 32; off; off >>= 1) v = fmaxf(v, __shfl_down(v, off));
    __syncthreads();
    if ((tid & 63) == 0) sm[tid >> 6] = v;
    __syncthreads();
    return fmaxf(fmaxf(sm[0], sm[1]), fmaxf(sm[2], sm[3]));
}
__device__ __forceinline__ float clampf(float v, float lo, float hi) {
    return fminf(fmaxf(v, lo), hi);
}

// ---------------- weight absmean (deterministic two-pass) ----------------
__global__ void absmean_partial(const float* __restrict__ w, int n, float* __restrict__ part) {
    __shared__ float sm[4];
    float sum = 0.f;
    for (int i = blockIdx.x * 256 + threadIdx.x; i < n; i += gridDim.x * 256)
        sum += fabsf(w[i]);
    sum = blk_sum(sum, sm);
    if (threadIdx.x == 0) part[blockIdx.x] = sum;
}

__global__ void absmean_final(const float* __restrict__ part, float* __restrict__ sw,
                              int n0, int n1, int n2, int n3) {
    int tid = threadIdx.x;  // 64 threads
    int ns[4] = {n0, n1, n2, n3};
    for (int m = 0; m < 4; ++m) {
        float v = part[m * 64 + tid];
        #pragma unroll
        for (int off = 32; off; off >>= 1) v += __shfl_down(v, off);
        if (tid == 0) sw[m] = v / (float)ns[m] + 1e-6f;
    }
}

// ---------------- weight quantization ----------------
__global__ void quant_w(const float* __restrict__ w, const float* __restrict__ swp,
                        float* __restrict__ wq, int n) {
    int i = blockIdx.x * 256 + threadIdx.x;
    if (i < n) {
        float v = w[i] / swp[0];
        wq[i] = rintf(clampf(v, -1.f, 1.f));
    }
}
// x_proj: [80][1536] -> transposed [1536][80]
__global__ void quant_w_T(const float* __restrict__ w, const float* __restrict__ swp,
                          float* __restrict__ wqT) {
    int i = blockIdx.x * 256 + threadIdx.x;
    if (i < PROJ_DIM * D_INNER) {
        int j = i / D_INNER, k = i % D_INNER;
        float v = w[i] / swp[0];
        wqT[k * PROJ_DIM + j] = rintf(clampf(v, -1.f, 1.f));
    }
}

// ---------------- fused center x2 + bitshift-norm + act quant ----------------
__global__ __launch_bounds__(256) void norm_quant(
    const float* __restrict__ x, const float* __restrict__ gamma,
    const float* __restrict__ swp, float* __restrict__ xq, float* __restrict__ s1) {
    int row = blockIdx.x, tid = threadIdx.x;
    const float* xr = x + (size_t)row * D_MODEL;
    __shared__ float sm[4];
    float v0 = xr[tid], v1 = xr[tid + 256], v2 = xr[tid + 512];
    // module-level centering
    float m1 = blk_sum(v0 + v1 + v2, sm) * (1.f / D_MODEL);
    v0 -= m1; v1 -= m1; v2 -= m1;
    // bitshift_norm centering
    float m2 = blk_sum(v0 + v1 + v2, sm) * (1.f / D_MODEL);
    v0 -= m2; v1 -= m2; v2 -= m2;
    float var = blk_sum(v0 * v0 + v1 * v1 + v2 * v2, sm) * (1.f / D_MODEL);
    float rms = sqrtf(var + 1e-6f);
    float k = fmaxf(rintf(log2f(rms)), 0.f);
    float inv = exp2f(-k);
    float g0 = gamma[tid], g1 = gamma[tid + 256], g2 = gamma[tid + 512];
    float h0 = v0 * inv * g0, h1 = v1 * inv * g1, h2 = v2 * inv * g2;
    float mx = blk_max(fmaxf(fabsf(h0), fmaxf(fabsf(h1), fabsf(h2))), sm);
    float sx = 127.f / (mx + 1e-6f);
    float* xo = xq + (size_t)row * D_MODEL;
    xo[tid]       = rintf(clampf(h0 * sx, -128.f, 127.f));
    xo[tid + 256] = rintf(clampf(h1 * sx, -128.f, 127.f));
    xo[tid + 512] = rintf(clampf(h2 * sx, -128.f, 127.f));
    if (tid == 0) s1[row] = swp[0] * (mx + 1e-6f) / 127.f;
}

// ---------------- generic row-wise |max| + act quant ----------------
__global__ void rowmax_quant(const float* __restrict__ in, int instride, int K,
                             const float* __restrict__ swp,
                             float* __restrict__ xq, float* __restrict__ sout) {
    int row = blockIdx.x, tid = threadIdx.x;
    const float* ir = in + (size_t)row * instride;
    __shared__ float sm[4];
    float mx = 0.f;
    for (int k = tid; k < K; k += 256) mx = fmaxf(mx, fabsf(ir[k]));
    mx = blk_max(mx, sm);
    float sx = 127.f / (mx + 1e-6f);
    for (int k = tid; k < K; k += 256)
        xq[(size_t)row * K + k] = rintf(clampf(ir[k] * sx, -128.f, 127.f));
    if (tid == 0) sout[row] = swp[0] * (mx + 1e-6f) / 127.f;
}

// ---------------- tiled GEMM: C[M,N] = (A[M,K] @ W[N,K]^T) * s[row] (+resid) ----------------
__global__ __launch_bounds__(256) void gemm_rowscale(
    const float* __restrict__ A, const float* __restrict__ W,
    const float* __restrict__ s, float* __restrict__ C,
    int M, int N, int K,
    const float* __restrict__ resid, const float* __restrict__ rg) {
    __shared__ float As[16][68];
    __shared__ float Ws[16][68];
    int bm = blockIdx.y * 64, bn = blockIdx.x * 64;
    int tid = threadIdx.x;
    int tx = tid & 15, ty = tid >> 4;
    float acc[4][4] = {};
    for (int k0 = 0; k0 < K; k0 += 16) {
        int idx = tid;
        #pragma unroll
        for (int u = 0; u < 4; ++u, idx += 256) {
            int r = idx >> 4, c = idx & 15;
            As[c][r] = A[(size_t)(bm + r) * K + k0 + c];
            Ws[c][r] = W[(size_t)(bn + r) * K + k0 + c];
        }
        __syncthreads();
        #pragma unroll
        for (int kk = 0; kk < 16; ++kk) {
            float a0 = As[kk][ty * 4 + 0], a1 = As[kk][ty * 4 + 1];
            float a2 = As[kk][ty * 4 + 2], a3 = As[kk][ty * 4 + 3];
            float w0 = Ws[kk][tx * 4 + 0], w1 = Ws[kk][tx * 4 + 1];
            float w2 = Ws[kk][tx * 4 + 2], w3 = Ws[kk][tx * 4 + 3];
            acc[0][0] = fmaf(a0, w0, acc[0][0]); acc[0][1] = fmaf(a0, w1, acc[0][1]);
            acc[0][2] = fmaf(a0, w2, acc[0][2]); acc[0][3] = fmaf(a0, w3, acc[0][3]);
            acc[1][0] = fmaf(a1, w0, acc[1][0]); acc[1][1] = fmaf(a1, w1, acc[1][1]);
            acc[1][2] = fmaf(a1, w2, acc[1][2]); acc[1][3] = fmaf(a1, w3, acc[1][3]);
            acc[2][0] = fmaf(a2, w0, acc[2][0]); acc[2][1] = fmaf(a2, w1, acc[2][1]);
            acc[2][2] = fmaf(a2, w2, acc[2][2]); acc[2][3] = fmaf(a2, w3, acc[2][3]);
            acc[3][0] = fmaf(a3, w0, acc[3][0]); acc[3][1] = fmaf(a3, w1, acc[3][1]);
            acc[3][2] = fmaf(a3, w2, acc[3][2]); acc[3][3] = fmaf(a3, w3, acc[3][3]);
        }
        __syncthreads();
    }
    int row0 = bm + ty * 4, col0 = bn + tx * 4;
    #pragma unroll
    for (int i = 0; i < 4; ++i) {
        float sc = s[row0 + i];
        #pragma unroll
        for (int j = 0; j < 4; ++j) {
            float v = acc[i][j] * sc;
            size_t o = (size_t)(row0 + i) * N + col0 + j;
            if (resid) v = resid[o] + v * rg[0];
            C[o] = v;
        }
    }
}

// ---------------- depthwise causal conv(4) + clip + smooth softplus ----------------
__global__ void conv_softplus(const float* __restrict__ xz, const float* __restrict__ cw,
                              const float* __restrict__ cb, float* __restrict__ xs) {
    int idx = blockIdx.x * 256 + threadIdx.x;
    if (idx >= Bb * Ll * D_INNER) return;
    int c = idx % D_INNER;
    int l = (idx / D_INNER) % Ll;
    int b = idx / (D_INNER * Ll);
    float acc = cb[c];
    #pragma unroll
    for (int k = 0; k < 4; ++k) {
        int t = l - 3 + k;
        if (t >= 0)
            acc = fmaf(cw[c * 4 + k], xz[((size_t)(b * Ll + t)) * XZ_DIM + c], acc);
    }
    acc = clampf(acc, -50.f, 50.f);
    xs[idx] = 0.5f * (acc + sqrtf(fmaf(acc, acc, 4.f)));
}

// ---------------- small GEMM: proj[2048,80] = (xq2 @ wqT) * s2 ----------------
__global__ __launch_bounds__(256) void gemm_row80(
    const float* __restrict__ xq, const float* __restrict__ wT,
    const float* __restrict__ s, float* __restrict__ proj) {
    int row = blockIdx.x, tid = threadIdx.x;
    __shared__ float a[D_INNER];
    for (int k = tid; k < D_INNER; k += 256) a[k] = xq[(size_t)row * D_INNER + k];
    __syncthreads();
    if (tid < PROJ_DIM) {
        float acc = 0.f;
        for (int k = 0; k < D_INNER; ++k)
            acc = fmaf(a[k], wT[k * PROJ_DIM + tid], acc);
        proj[row * PROJ_DIM + tid] = acc * s[row];
    }
}

// ---------------- fused SSM scan + C-contraction + z gate ----------------
__global__ __launch_bounds__(256) void scan_gate(
    const float* __restrict__ xs, const float* __restrict__ dmod,
    const float* __restrict__ proj, const float* __restrict__ xz,
    const float* __restrict__ base, const float* __restrict__ shifts,
    float* __restrict__ yg) {
    int gid = blockIdx.x * 256 + threadIdx.x;   // 0..3071
    int b = gid / D_INNER, d = gid % D_INNER;
    float h[D_STATE], bs[D_STATE], asc[D_STATE];
    #pragma unroll
    for (int n = 0; n < D_STATE; ++n) {
        h[n] = 0.f;
        bs[n] = base[d * D_STATE + n];
        asc[n] = exp2f(-shifts[d * D_STATE + n]);
    }
    for (int t = 0; t < Ll; ++t) {
        size_t r = (size_t)b * Ll + t;
        float dm = dmod[r * D_INNER + d];
        float xv = xs[r * D_INNER + d];
        float dtv = clampf(0.5f * (dm + sqrtf(fmaf(dm, dm, 4.f))) * 0.01f, 0.f, 0.1f);
        float xdt = xv * dtv;
        const float* pr = proj + r * PROJ_DIM;
        float y = 0.f;
        #pragma unroll
        for (int n = 0; n < D_STATE; ++n) {
            float u = clampf(xdt * pr[DT_RANK + n], -100.f, 100.f);
            float a = clampf(bs[n] + dm, 0.f, 32000.f) * asc[n];
            h[n] = fmaf(a, h[n], u);
            float hc = clampf(h[n], -1000.f, 1000.f);
            y = fmaf(hc, pr[DT_RANK + D_STATE + n], y);
        }
        float z = xz[r * XZ_DIM + D_INNER + d];
        float g = 0.5f * (z * __frsqrt_rn(fmaf(z, z, 1.f)) + 1.f);
        // use precise path to match reference closely:
        g = 0.5f * (z / sqrtf(fmaf(z, z, 1.f)) + 1.f);
        yg[r * D_INNER + d] = y * g;
    }
}

// ---------------- launcher ----------------
extern "C" void kernel_launch(void* const* d_in, const int* in_sizes, int n_in,
                              void* d_out, int out_size, void* d_ws, size_t ws_size,
                              hipStream_t stream) {
    const float* hs    = (const float*)d_in[0];
    const float* gamma = (const float*)d_in[1];
    const float* w_in  = (const float*)d_in[2];
    const float* cw    = (const float*)d_in[3];
    const float* cb    = (const float*)d_in[4];
    const float* w_xp  = (const float*)d_in[5];
    const float* w_dt  = (const float*)d_in[6];
    const float* w_out = (const float*)d_in[7];
    const float* base  = (const float*)d_in[8];
    const float* rg    = (const float*)d_in[9];
    const float* shifts= (const float*)d_in[10];
    float* ws  = (float*)d_ws;
    float* out = (float*)d_out;

    const int n_in_w = XZ_DIM * D_MODEL;      // 2359296
    const int n_xp_w = PROJ_DIM * D_INNER;    // 122880
    const int n_dt_w = D_INNER * DT_RANK;     // 73728
    const int n_out_w = D_MODEL * D_INNER;    // 1179648

    // 1. weight scales
    absmean_partial<<<64, 256, 0, stream>>>(w_in,  n_in_w,  ws + OFF_PART + 0);
    absmean_partial<<<64, 256, 0, stream>>>(w_xp,  n_xp_w,  ws + OFF_PART + 64);
    absmean_partial<<<64, 256, 0, stream>>>(w_dt,  n_dt_w,  ws + OFF_PART + 128);
    absmean_partial<<<64, 256, 0, stream>>>(w_out, n_out_w, ws + OFF_PART + 192);
    absmean_final<<<1, 64, 0, stream>>>(ws + OFF_PART, ws + OFF_SW,
                                        n_in_w, n_xp_w, n_dt_w, n_out_w);
    // 2. ternary weights
    quant_w  <<<(n_in_w + 255) / 256, 256, 0, stream>>>(w_in,  ws + OFF_SW + 0, ws + OFF_WQIN, n_in_w);
    quant_w_T<<<(n_xp_w + 255) / 256, 256, 0, stream>>>(w_xp,  ws + OFF_SW + 1, ws + OFF_WQXPT);
    quant_w  <<<(n_dt_w + 255) / 256, 256, 0, stream>>>(w_dt,  ws + OFF_SW + 2, ws + OFF_WQDT, n_dt_w);
    quant_w  <<<(n_out_w + 255) / 256, 256, 0, stream>>>(w_out, ws + OFF_SW + 3, ws + OFF_WQOUT, n_out_w);
    // 3. norm + act quant
    norm_quant<<<ROWS, 256, 0, stream>>>(hs, gamma, ws + OFF_SW + 0, ws + OFF_XQ1, ws + OFF_S1);
    // 4. in_proj GEMM -> xz
    gemm_rowscale<<<dim3(XZ_DIM / 64, ROWS / 64), 256, 0, stream>>>(
        ws + OFF_XQ1, ws + OFF_WQIN, ws + OFF_S1, ws + OFF_XZ,
        ROWS, XZ_DIM, D_MODEL, nullptr, nullptr);
    // 5. conv + softplus
    conv_softplus<<<(Bb * Ll * D_INNER + 255) / 256, 256, 0, stream>>>(
        ws + OFF_XZ, cw, cb, ws + OFF_XS);
    // 6. quant for x_proj
    rowmax_quant<<<ROWS, 256, 0, stream>>>(ws + OFF_XS, D_INNER, D_INNER,
                                           ws + OFF_SW + 1, ws + OFF_XQ2, ws + OFF_S2);
    // 7. x_proj GEMM -> proj[2048,80]
    gemm_row80<<<ROWS, 256, 0, stream>>>(ws + OFF_XQ2, ws + OFF_WQXPT, ws + OFF_S2, ws + OFF_PROJ);
    // 8. dt quant (first 48 cols of proj)
    rowmax_quant<<<ROWS, 256, 0, stream>>>(ws + OFF_PROJ, PROJ_DIM, DT_RANK,
                                           ws + OFF_SW + 2, ws + OFF_XQ3, ws + OFF_S3);
    // 9. dt_proj GEMM -> decay_mod
    gemm_rowscale<<<dim3(D_INNER / 64, ROWS / 64), 256, 0, stream>>>(
        ws + OFF_XQ3, ws + OFF_WQDT, ws + OFF_S3, ws + OFF_DMOD,
        ROWS, D_INNER, DT_RANK, nullptr, nullptr);
    // 10. fused scan + gate
    scan_gate<<<(Bb * D_INNER) / 256, 256, 0, stream>>>(
        ws + OFF_XS, ws + OFF_DMOD, ws + OFF_PROJ, ws + OFF_XZ, base, shifts, ws + OFF_YG);
    // 11. quant for out_proj
    rowmax_quant<<<ROWS, 256, 0, stream>>>(ws + OFF_YG, D_INNER, D_INNER,
                                           ws + OFF_SW + 3, ws + OFF_XQ4, ws + OFF_S4);
    // 12. out_proj GEMM + residual epilogue -> d_out
    gemm_rowscale<<<dim3(D_MODEL / 64, ROWS / 64), 256, 0, stream>>>(
        ws + OFF_XQ4, ws + OFF_WQOUT, ws + OFF_S4, out,
        ROWS, D_MODEL, D_INNER, hs, rg);
}

// Round 2
// 510.019 us; speedup vs baseline: 4.4310x; 4.4310x over previous
//
#include <hip/hip_runtime.h>
#include <math.h>

// ---------------- problem constants ----------------
#define D_MODEL 768
#define D_STATE 16
#define DT_RANK 48
#define D_INNER 1536           // 2*D_MODEL
#define XZ_DIM  3072           // 2*D_INNER
#define PROJ_DIM 80            // DT_RANK + 2*D_STATE
#define Bb 2
#define Ll 1024
#define ROWS (Bb*Ll)           // 2048

// ---------------- ws layout (float offsets) ----------------
#define OFF_PART   0u                     // 4 matrices x 64 partials
#define OFF_SW     256u                   // 4 scalars
#define OFF_WQIN   512u                   // 3072x768
#define OFF_WQXPT  (OFF_WQIN  + 2359296u) // 1536x80 (transposed)
#define OFF_WQDT   (OFF_WQXPT + 122880u)  // 1536x48
#define OFF_WQOUT  (OFF_WQDT  + 73728u)   // 768x1536
#define OFF_XQ1    (OFF_WQOUT + 1179648u) // 2048x768
#define OFF_S1     (OFF_XQ1   + 1572864u) // 2048
#define OFF_XZ     (OFF_S1    + 2048u)    // 2048x3072
#define OFF_XS     (OFF_XZ    + 6291456u) // 2048x1536
#define OFF_XQ2    (OFF_XS    + 3145728u) // 2048x1536 (later reused as xdtT [1536][2][1024])
#define OFF_S2     (OFF_XQ2   + 3145728u) // 2048
#define OFF_PROJ   (OFF_S2    + 2048u)    // 2048x80
#define OFF_XQ3    (OFF_PROJ  + 163840u)  // 2048x48
#define OFF_S3     (OFF_XQ3   + 98304u)   // 2048
#define OFF_DMOD   (OFF_S3    + 2048u)    // 2048x1536
#define OFF_YG     (OFF_DMOD  + 3145728u) // 2048x1536
#define OFF_XQ4    (OFF_YG    + 3145728u) // 2048x1536 (first reused as dmT [1536][2][1024])
#define OFF_S4     (OFF_XQ4   + 3145728u) // 2048

// ---------------- helpers ----------------
__device__ __forceinline__ float blk_sum(float v, float* sm) {
    int tid = threadIdx.x;
    #pragma unroll
    for (int off = 32; off; off >>= 1) v += __shfl_down(v, off);
    __syncthreads();
    if ((tid & 63) == 0) sm[tid >> 6] = v;
    __syncthreads();
    return (sm[0] + sm[1]) + (sm[2] + sm[3]);
}
__device__ __forceinline__ float blk_max(float v, float* sm) {
    int tid = threadIdx.x;
    #pragma unroll
    for (int off = 32; off; off >>= 1) v = fmaxf(v, __shfl_down(v, off));
    __syncthreads();
    if ((tid & 63) == 0) sm[tid >> 6] = v;
    __syncthreads();
    return fmaxf(fmaxf(sm[0], sm[1]), fmaxf(sm[2], sm[3]));
}
__device__ __forceinline__ float clampf(float v, float lo, float hi) {
    return fminf(fmaxf(v, lo), hi);
}

// ---------------- weight absmean (deterministic two-pass) ----------------
__global__ void absmean_partial(const float* __restrict__ w, int n, float* __restrict__ part) {
    __shared__ float sm[4];
    float sum = 0.f;
    for (int i = blockIdx.x * 256 + threadIdx.x; i < n; i += gridDim.x * 256)
        sum += fabsf(w[i]);
    sum = blk_sum(sum, sm);
    if (threadIdx.x == 0) part[blockIdx.x] = sum;
}

__global__ void absmean_final(const float* __restrict__ part, float* __restrict__ sw,
                              int n0, int n1, int n2, int n3) {
    int tid = threadIdx.x;  // 64 threads
    int ns[4] = {n0, n1, n2, n3};
    for (int m = 0; m < 4; ++m) {
        float v = part[m * 64 + tid];
        #pragma unroll
        for (int off = 32; off; off >>= 1) v += __shfl_down(v, off);
        if (tid == 0) sw[m] = v / (float)ns[m] + 1e-6f;
    }
}

// ---------------- weight quantization ----------------
__global__ void quant_w(const float* __restrict__ w, const float* __restrict__ swp,
                        float* __restrict__ wq, int n) {
    int i = blockIdx.x * 256 + threadIdx.x;
    if (i < n) {
        float v = w[i] / swp[0];
        wq[i] = rintf(clampf(v, -1.f, 1.f));
    }
}
// x_proj: [80][1536] -> transposed [1536][80]
__global__ void quant_w_T(const float* __restrict__ w, const float* __restrict__ swp,
                          float* __restrict__ wqT) {
    int i = blockIdx.x * 256 + threadIdx.x;
    if (i < PROJ_DIM * D_INNER) {
        int j = i / D_INNER, k = i % D_INNER;
        float v = w[i] / swp[0];
        wqT[k * PROJ_DIM + j] = rintf(clampf(v, -1.f, 1.f));
    }
}

// ---------------- fused center x2 + bitshift-norm + act quant ----------------
__global__ __launch_bounds__(256) void norm_quant(
    const float* __restrict__ x, const float* __restrict__ gamma,
    const float* __restrict__ swp, float* __restrict__ xq, float* __restrict__ s1) {
    int row = blockIdx.x, tid = threadIdx.x;
    const float* xr = x + (size_t)row * D_MODEL;
    __shared__ float sm[4];
    float v0 = xr[tid], v1 = xr[tid + 256], v2 = xr[tid + 512];
    float m1 = blk_sum(v0 + v1 + v2, sm) * (1.f / D_MODEL);
    v0 -= m1; v1 -= m1; v2 -= m1;
    float m2 = blk_sum(v0 + v1 + v2, sm) * (1.f / D_MODEL);
    v0 -= m2; v1 -= m2; v2 -= m2;
    float var = blk_sum(v0 * v0 + v1 * v1 + v2 * v2, sm) * (1.f / D_MODEL);
    float rms = sqrtf(var + 1e-6f);
    float k = fmaxf(rintf(log2f(rms)), 0.f);
    float inv = exp2f(-k);
    float g0 = gamma[tid], g1 = gamma[tid + 256], g2 = gamma[tid + 512];
    float h0 = v0 * inv * g0, h1 = v1 * inv * g1, h2 = v2 * inv * g2;
    float mx = blk_max(fmaxf(fabsf(h0), fmaxf(fabsf(h1), fabsf(h2))), sm);
    float sx = 127.f / (mx + 1e-6f);
    float* xo = xq + (size_t)row * D_MODEL;
    xo[tid]       = rintf(clampf(h0 * sx, -128.f, 127.f));
    xo[tid + 256] = rintf(clampf(h1 * sx, -128.f, 127.f));
    xo[tid + 512] = rintf(clampf(h2 * sx, -128.f, 127.f));
    if (tid == 0) s1[row] = swp[0] * (mx + 1e-6f) / 127.f;
}

// ---------------- generic row-wise |max| + act quant ----------------
__global__ void rowmax_quant(const float* __restrict__ in, int instride, int K,
                             const float* __restrict__ swp,
                             float* __restrict__ xq, float* __restrict__ sout) {
    int row = blockIdx.x, tid = threadIdx.x;
    const float* ir = in + (size_t)row * instride;
    __shared__ float sm[4];
    float mx = 0.f;
    for (int k = tid; k < K; k += 256) mx = fmaxf(mx, fabsf(ir[k]));
    mx = blk_max(mx, sm);
    float sx = 127.f / (mx + 1e-6f);
    for (int k = tid; k < K; k += 256)
        xq[(size_t)row * K + k] = rintf(clampf(ir[k] * sx, -128.f, 127.f));
    if (tid == 0) sout[row] = swp[0] * (mx + 1e-6f) / 127.f;
}

// ---------------- tiled GEMM: C[M,N] = (A[M,K] @ W[N,K]^T) * s[row] (+resid) ----------------
__global__ __launch_bounds__(256) void gemm_rowscale(
    const float* __restrict__ A, const float* __restrict__ W,
    const float* __restrict__ s, float* __restrict__ C,
    int M, int N, int K,
    const float* __restrict__ resid, const float* __restrict__ rg) {
    __shared__ float As[16][68];
    __shared__ float Ws[16][68];
    int bm = blockIdx.y * 64, bn = blockIdx.x * 64;
    int tid = threadIdx.x;
    int tx = tid & 15, ty = tid >> 4;
    float acc[4][4] = {};
    for (int k0 = 0; k0 < K; k0 += 16) {
        int idx = tid;
        #pragma unroll
        for (int u = 0; u < 4; ++u, idx += 256) {
            int r = idx >> 4, c = idx & 15;
            As[c][r] = A[(size_t)(bm + r) * K + k0 + c];
            Ws[c][r] = W[(size_t)(bn + r) * K + k0 + c];
        }
        __syncthreads();
        #pragma unroll
        for (int kk = 0; kk < 16; ++kk) {
            float a0 = As[kk][ty * 4 + 0], a1 = As[kk][ty * 4 + 1];
            float a2 = As[kk][ty * 4 + 2], a3 = As[kk][ty * 4 + 3];
            float w0 = Ws[kk][tx * 4 + 0], w1 = Ws[kk][tx * 4 + 1];
            float w2 = Ws[kk][tx * 4 + 2], w3 = Ws[kk][tx * 4 + 3];
            acc[0][0] = fmaf(a0, w0, acc[0][0]); acc[0][1] = fmaf(a0, w1, acc[0][1]);
            acc[0][2] = fmaf(a0, w2, acc[0][2]); acc[0][3] = fmaf(a0, w3, acc[0][3]);
            acc[1][0] = fmaf(a1, w0, acc[1][0]); acc[1][1] = fmaf(a1, w1, acc[1][1]);
            acc[1][2] = fmaf(a1, w2, acc[1][2]); acc[1][3] = fmaf(a1, w3, acc[1][3]);
            acc[2][0] = fmaf(a2, w0, acc[2][0]); acc[2][1] = fmaf(a2, w1, acc[2][1]);
            acc[2][2] = fmaf(a2, w2, acc[2][2]); acc[2][3] = fmaf(a2, w3, acc[2][3]);
            acc[3][0] = fmaf(a3, w0, acc[3][0]); acc[3][1] = fmaf(a3, w1, acc[3][1]);
            acc[3][2] = fmaf(a3, w2, acc[3][2]); acc[3][3] = fmaf(a3, w3, acc[3][3]);
        }
        __syncthreads();
    }
    int row0 = bm + ty * 4, col0 = bn + tx * 4;
    #pragma unroll
    for (int i = 0; i < 4; ++i) {
        float sc = s[row0 + i];
        #pragma unroll
        for (int j = 0; j < 4; ++j) {
            float v = acc[i][j] * sc;
            size_t o = (size_t)(row0 + i) * N + col0 + j;
            if (resid) v = resid[o] + v * rg[0];
            C[o] = v;
        }
    }
}

// ---------------- depthwise causal conv(4) + clip + smooth softplus ----------------
__global__ void conv_softplus(const float* __restrict__ xz, const float* __restrict__ cw,
                              const float* __restrict__ cb, float* __restrict__ xs) {
    int idx = blockIdx.x * 256 + threadIdx.x;
    if (idx >= Bb * Ll * D_INNER) return;
    int c = idx % D_INNER;
    int l = (idx / D_INNER) % Ll;
    int b = idx / (D_INNER * Ll);
    float acc = cb[c];
    #pragma unroll
    for (int k = 0; k < 4; ++k) {
        int t = l - 3 + k;
        if (t >= 0)
            acc = fmaf(cw[c * 4 + k], xz[((size_t)(b * Ll + t)) * XZ_DIM + c], acc);
    }
    acc = clampf(acc, -50.f, 50.f);
    xs[idx] = 0.5f * (acc + sqrtf(fmaf(acc, acc, 4.f)));
}

// ---------------- small GEMM: proj[2048,80] = (xq2 @ wqT) * s2 ----------------
__global__ __launch_bounds__(256) void gemm_row80(
    const float* __restrict__ xq, const float* __restrict__ wT,
    const float* __restrict__ s, float* __restrict__ proj) {
    int row = blockIdx.x, tid = threadIdx.x;
    __shared__ float a[D_INNER];
    for (int k = tid; k < D_INNER; k += 256) a[k] = xq[(size_t)row * D_INNER + k];
    __syncthreads();
    if (tid < PROJ_DIM) {
        float acc = 0.f;
        for (int k = 0; k < D_INNER; ++k)
            acc = fmaf(a[k], wT[k * PROJ_DIM + tid], acc);
        proj[row * PROJ_DIM + tid] = acc * s[row];
    }
}

// ---------------- prep: dtv/xdt compute + LDS-tiled transpose to [d][b][l] ----------------
__global__ __launch_bounds__(256) void prep_transpose(
    const float* __restrict__ dmod, const float* __restrict__ xs,
    float* __restrict__ dmT, float* __restrict__ xdtT) {
    __shared__ float t0[64][65];
    __shared__ float t1[64][65];
    int r0 = blockIdx.y * 64;   // row tile (within [0,2048))
    int d0 = blockIdx.x * 64;   // col tile (within [0,1536))
    int tid = threadIdx.x;
    #pragma unroll
    for (int i = 0; i < 16; ++i) {
        int idx = tid + i * 256;
        int rr = idx >> 6, cc = idx & 63;
        size_t src = (size_t)(r0 + rr) * D_INNER + d0 + cc;
        float dm = dmod[src];
        float xv = xs[src];
        float dtv = clampf(0.5f * (dm + sqrtf(fmaf(dm, dm, 4.f))) * 0.01f, 0.f, 0.1f);
        t0[cc][rr] = dm;
        t1[cc][rr] = xv * dtv;
    }
    __syncthreads();
    int b = r0 >> 10;
    int lbase = r0 & 1023;
    #pragma unroll
    for (int i = 0; i < 16; ++i) {
        int idx = tid + i * 256;
        int dd = idx >> 6, ll = idx & 63;
        size_t dst = (size_t)((d0 + dd) * Bb + b) * Ll + lbase + ll;
        dmT[dst]  = t0[dd][ll];
        xdtT[dst] = t1[dd][ll];
    }
}

// ---------------- chunked parallel scan + C-contraction + z gate ----------------
#define NCHUNK 32
#define CLEN   32   // NCHUNK*CLEN == Ll
__global__ __launch_bounds__(512) void scan_chunked(
    const float* __restrict__ dmT, const float* __restrict__ xdtT,
    const float* __restrict__ proj, const float* __restrict__ xz,
    const float* __restrict__ base, const float* __restrict__ shifts,
    float* __restrict__ yg) {
    int bid = blockIdx.x;          // 0..Bb*D_INNER-1
    int d = bid >> 1, b = bid & 1;
    int tid = threadIdx.x;
    int chunk = tid >> 4, n = tid & 15;
    __shared__ float dmL[Ll];
    __shared__ float xdtL[Ll];
    __shared__ float Ps[NCHUNK][16];
    __shared__ float Hs[NCHUNK][16];
    __shared__ float Cin[NCHUNK][16];
    size_t tbase = (size_t)bid * Ll;   // (d*2+b)*1024
    for (int i = tid; i < Ll; i += 512) {
        dmL[i]  = dmT[tbase + i];
        xdtL[i] = xdtT[tbase + i];
    }
    float bs_n  = base[d * D_STATE + n];
    float asc_n = exp2f(-shifts[d * D_STATE + n]);
    __syncthreads();
    // pass A: local scan from 0, record (prod a, h_end)
    float P = 1.f, h = 0.f;
    int l0 = chunk * CLEN;
    const float* projR = proj + (size_t)(b * Ll) * PROJ_DIM;
    for (int s = 0; s < CLEN; ++s) {
        int l = l0 + s;
        float dm = dmL[l], xdt = xdtL[l];
        float Bv = projR[(size_t)l * PROJ_DIM + DT_RANK + n];
        float u = clampf(xdt * Bv, -100.f, 100.f);
        float a = clampf(bs_n + dm, 0.f, 32000.f) * asc_n;
        h = fmaf(a, h, u);
        P *= a;
    }
    Ps[chunk][n] = P;
    Hs[chunk][n] = h;
    __syncthreads();
    // mid-scan over chunk summaries (serial, 16 threads)
    if (tid < 16) {
        float carry = 0.f;
        for (int c = 0; c < NCHUNK; ++c) {
            Cin[c][tid] = carry;
            carry = fmaf(Ps[c][tid], carry, Hs[c][tid]);
        }
    }
    __syncthreads();
    // pass C: re-scan with carry-in, fused y = sum_n clip(h)*C, gate, store
    h = Cin[chunk][n];
    for (int s = 0; s < CLEN; ++s) {
        int l = l0 + s;
        float dm = dmL[l], xdt = xdtL[l];
        size_t pr = (size_t)l * PROJ_DIM;
        float Bv = projR[pr + DT_RANK + n];
        float Cv = projR[pr + DT_RANK + D_STATE + n];
        float u = clampf(xdt * Bv, -100.f, 100.f);
        float a = clampf(bs_n + dm, 0.f, 32000.f) * asc_n;
        h = fmaf(a, h, u);
        float hc = clampf(h, -1000.f, 1000.f);
        float y = hc * Cv;
        y += __shfl_xor(y, 1);
        y += __shfl_xor(y, 2);
        y += __shfl_xor(y, 4);
        y += __shfl_xor(y, 8);
        if (n == 0) {
            size_t r = (size_t)b * Ll + l;
            float z = xz[r * XZ_DIM + D_INNER + d];
            float g = 0.5f * (z / sqrtf(fmaf(z, z, 1.f)) + 1.f);
            yg[r * D_INNER + d] = y * g;
        }
    }
}

// ---------------- launcher ----------------
extern "C" void kernel_launch(void* const* d_in, const int* in_sizes, int n_in,
                              void* d_out, int out_size, void* d_ws, size_t ws_size,
                              hipStream_t stream) {
    const float* hs    = (const float*)d_in[0];
    const float* gamma = (const float*)d_in[1];
    const float* w_in  = (const float*)d_in[2];
    const float* cw    = (const float*)d_in[3];
    const float* cb    = (const float*)d_in[4];
    const float* w_xp  = (const float*)d_in[5];
    const float* w_dt  = (const float*)d_in[6];
    const float* w_out = (const float*)d_in[7];
    const float* base  = (const float*)d_in[8];
    const float* rg    = (const float*)d_in[9];
    const float* shifts= (const float*)d_in[10];
    float* ws  = (float*)d_ws;
    float* out = (float*)d_out;

    const int n_in_w = XZ_DIM * D_MODEL;      // 2359296
    const int n_xp_w = PROJ_DIM * D_INNER;    // 122880
    const int n_dt_w = D_INNER * DT_RANK;     // 73728
    const int n_out_w = D_MODEL * D_INNER;    // 1179648

    // 1. weight scales
    absmean_partial<<<64, 256, 0, stream>>>(w_in,  n_in_w,  ws + OFF_PART + 0);
    absmean_partial<<<64, 256, 0, stream>>>(w_xp,  n_xp_w,  ws + OFF_PART + 64);
    absmean_partial<<<64, 256, 0, stream>>>(w_dt,  n_dt_w,  ws + OFF_PART + 128);
    absmean_partial<<<64, 256, 0, stream>>>(w_out, n_out_w, ws + OFF_PART + 192);
    absmean_final<<<1, 64, 0, stream>>>(ws + OFF_PART, ws + OFF_SW,
                                        n_in_w, n_xp_w, n_dt_w, n_out_w);
    // 2. ternary weights
    quant_w  <<<(n_in_w + 255) / 256, 256, 0, stream>>>(w_in,  ws + OFF_SW + 0, ws + OFF_WQIN, n_in_w);
    quant_w_T<<<(n_xp_w + 255) / 256, 256, 0, stream>>>(w_xp,  ws + OFF_SW + 1, ws + OFF_WQXPT);
    quant_w  <<<(n_dt_w + 255) / 256, 256, 0, stream>>>(w_dt,  ws + OFF_SW + 2, ws + OFF_WQDT, n_dt_w);
    quant_w  <<<(n_out_w + 255) / 256, 256, 0, stream>>>(w_out, ws + OFF_SW + 3, ws + OFF_WQOUT, n_out_w);
    // 3. norm + act quant
    norm_quant<<<ROWS, 256, 0, stream>>>(hs, gamma, ws + OFF_SW + 0, ws + OFF_XQ1, ws + OFF_S1);
    // 4. in_proj GEMM -> xz
    gemm_rowscale<<<dim3(XZ_DIM / 64, ROWS / 64), 256, 0, stream>>>(
        ws + OFF_XQ1, ws + OFF_WQIN, ws + OFF_S1, ws + OFF_XZ,
        ROWS, XZ_DIM, D_MODEL, nullptr, nullptr);
    // 5. conv + softplus
    conv_softplus<<<(Bb * Ll * D_INNER + 255) / 256, 256, 0, stream>>>(
        ws + OFF_XZ, cw, cb, ws + OFF_XS);
    // 6. quant for x_proj
    rowmax_quant<<<ROWS, 256, 0, stream>>>(ws + OFF_XS, D_INNER, D_INNER,
                                           ws + OFF_SW + 1, ws + OFF_XQ2, ws + OFF_S2);
    // 7. x_proj GEMM -> proj[2048,80]
    gemm_row80<<<ROWS, 256, 0, stream>>>(ws + OFF_XQ2, ws + OFF_WQXPT, ws + OFF_S2, ws + OFF_PROJ);
    // 8. dt quant (first 48 cols of proj)
    rowmax_quant<<<ROWS, 256, 0, stream>>>(ws + OFF_PROJ, PROJ_DIM, DT_RANK,
                                           ws + OFF_SW + 2, ws + OFF_XQ3, ws + OFF_S3);
    // 9. dt_proj GEMM -> decay_mod
    gemm_rowscale<<<dim3(D_INNER / 64, ROWS / 64), 256, 0, stream>>>(
        ws + OFF_XQ3, ws + OFF_WQDT, ws + OFF_S3, ws + OFF_DMOD,
        ROWS, D_INNER, DT_RANK, nullptr, nullptr);
    // 10a. prep: dtv/xdt + transpose to [d][b][l] (reuse XQ4 for dmT, XQ2 for xdtT)
    prep_transpose<<<dim3(D_INNER / 64, ROWS / 64), 256, 0, stream>>>(
        ws + OFF_DMOD, ws + OFF_XS, ws + OFF_XQ4, ws + OFF_XQ2);
    // 10b. chunked scan + gate
    scan_chunked<<<Bb * D_INNER, 512, 0, stream>>>(
        ws + OFF_XQ4, ws + OFF_XQ2, ws + OFF_PROJ, ws + OFF_XZ, base, shifts, ws + OFF_YG);
    // 11. quant for out_proj
    rowmax_quant<<<ROWS, 256, 0, stream>>>(ws + OFF_YG, D_INNER, D_INNER,
                                           ws + OFF_SW + 3, ws + OFF_XQ4, ws + OFF_S4);
    // 12. out_proj GEMM + residual epilogue -> d_out
    gemm_rowscale<<<dim3(D_MODEL / 64, ROWS / 64), 256, 0, stream>>>(
        ws + OFF_XQ4, ws + OFF_WQOUT, ws + OFF_S4, out,
        ROWS, D_MODEL, D_INNER, hs, rg);
}

// Round 3
// 344.945 us; speedup vs baseline: 6.5515x; 1.4786x over previous
//
#include <hip/hip_runtime.h>
#include <hip/hip_bf16.h>
#include <math.h>

// ---------------- problem constants ----------------
#define D_MODEL 768
#define D_STATE 16
#define DT_RANK 48
#define D_INNER 1536           // 2*D_MODEL
#define XZ_DIM  3072           // 2*D_INNER
#define PROJ_DIM 80            // DT_RANK + 2*D_STATE
#define Bb 2
#define Ll 1024
#define ROWS (Bb*Ll)           // 2048

// ---------------- ws layout (float offsets; bf16 buffers reuse same regions) ----------------
#define OFF_PART   0u                     // 4 matrices x 64 partials
#define OFF_SW     256u                   // 4 scalars
#define OFF_WQIN   512u                   // bf16 [3072][768]
#define OFF_WQXPT  (OFF_WQIN  + 2359296u) // f32 [1536][80] (transposed)
#define OFF_WQDT   (OFF_WQXPT + 122880u)  // f32 [1536][48]
#define OFF_WQOUT  (OFF_WQDT  + 73728u)   // bf16 [768][1536]
#define OFF_XQ1    (OFF_WQOUT + 1179648u) // bf16 [2048][768]
#define OFF_S1     (OFF_XQ1   + 1572864u) // 2048
#define OFF_XZ     (OFF_S1    + 2048u)    // f32 [2048][3072]
#define OFF_XS     (OFF_XZ    + 6291456u) // f32 [2048][1536]
#define OFF_XQ2    (OFF_XS    + 3145728u) // f32 2048x1536 (later reused as xdtT [1536][2][1024])
#define OFF_S2     (OFF_XQ2   + 3145728u) // 2048
#define OFF_PROJ   (OFF_S2    + 2048u)    // 2048x80
#define OFF_XQ3    (OFF_PROJ  + 163840u)  // f32 [2048][48]
#define OFF_S3     (OFF_XQ3   + 98304u)   // 2048
#define OFF_DMOD   (OFF_S3    + 2048u)    // f32 [2048][1536]
#define OFF_YG     (OFF_DMOD  + 3145728u) // f32 [2048][1536]
#define OFF_XQ4    (OFF_YG    + 3145728u) // dmT f32 [1536][2][1024], then bf16 [2048][1536]
#define OFF_S4     (OFF_XQ4   + 3145728u) // 2048

typedef short sh8 __attribute__((ext_vector_type(8)));
typedef float f32x4 __attribute__((ext_vector_type(4)));

// ---------------- helpers ----------------
__device__ __forceinline__ float blk_sum(float v, float* sm) {
    int tid = threadIdx.x;
    #pragma unroll
    for (int off = 32; off; off >>= 1) v += __shfl_down(v, off);
    __syncthreads();
    if ((tid & 63) == 0) sm[tid >> 6] = v;
    __syncthreads();
    return (sm[0] + sm[1]) + (sm[2] + sm[3]);
}
__device__ __forceinline__ float blk_max(float v, float* sm) {
    int tid = threadIdx.x;
    #pragma unroll
    for (int off = 32; off; off >>= 1) v = fmaxf(v, __shfl_down(v, off));
    __syncthreads();
    if ((tid & 63) == 0) sm[tid >> 6] = v;
    __syncthreads();
    return fmaxf(fmaxf(sm[0], sm[1]), fmaxf(sm[2], sm[3]));
}
__device__ __forceinline__ float clampf(float v, float lo, float hi) {
    return fminf(fmaxf(v, lo), hi);
}
__device__ __forceinline__ void gload_lds16(const __hip_bfloat16* g, __hip_bfloat16* l) {
    __builtin_amdgcn_global_load_lds(
        (const __attribute__((address_space(1))) void*)g,
        (__attribute__((address_space(3))) void*)l, 16, 0, 0);
}

// ---------------- weight absmean (deterministic two-pass) ----------------
__global__ void absmean_partial(const float* __restrict__ w, int n, float* __restrict__ part) {
    __shared__ float sm[4];
    float sum = 0.f;
    for (int i = blockIdx.x * 256 + threadIdx.x; i < n; i += gridDim.x * 256)
        sum += fabsf(w[i]);
    sum = blk_sum(sum, sm);
    if (threadIdx.x == 0) part[blockIdx.x] = sum;
}

__global__ void absmean_final(const float* __restrict__ part, float* __restrict__ sw,
                              int n0, int n1, int n2, int n3) {
    int tid = threadIdx.x;  // 64 threads
    int ns[4] = {n0, n1, n2, n3};
    for (int m = 0; m < 4; ++m) {
        float v = part[m * 64 + tid];
        #pragma unroll
        for (int off = 32; off; off >>= 1) v += __shfl_down(v, off);
        if (tid == 0) sw[m] = v / (float)ns[m] + 1e-6f;
    }
}

// ---------------- weight quantization ----------------
__global__ void quant_w(const float* __restrict__ w, const float* __restrict__ swp,
                        float* __restrict__ wq, int n) {
    int i = blockIdx.x * 256 + threadIdx.x;
    if (i < n) {
        float v = w[i] / swp[0];
        wq[i] = rintf(clampf(v, -1.f, 1.f));
    }
}
__global__ void quant_w_bf16(const float* __restrict__ w, const float* __restrict__ swp,
                             __hip_bfloat16* __restrict__ wq, int n) {
    int i = blockIdx.x * 256 + threadIdx.x;
    if (i < n) {
        float v = w[i] / swp[0];
        wq[i] = __float2bfloat16(rintf(clampf(v, -1.f, 1.f)));
    }
}
// x_proj: [80][1536] -> transposed [1536][80]
__global__ void quant_w_T(const float* __restrict__ w, const float* __restrict__ swp,
                          float* __restrict__ wqT) {
    int i = blockIdx.x * 256 + threadIdx.x;
    if (i < PROJ_DIM * D_INNER) {
        int j = i / D_INNER, k = i % D_INNER;
        float v = w[i] / swp[0];
        wqT[k * PROJ_DIM + j] = rintf(clampf(v, -1.f, 1.f));
    }
}

// ---------------- fused center x2 + bitshift-norm + act quant (bf16 out) ----------------
__global__ __launch_bounds__(256) void norm_quant(
    const float* __restrict__ x, const float* __restrict__ gamma,
    const float* __restrict__ swp, __hip_bfloat16* __restrict__ xq, float* __restrict__ s1) {
    int row = blockIdx.x, tid = threadIdx.x;
    const float* xr = x + (size_t)row * D_MODEL;
    __shared__ float sm[4];
    float v0 = xr[tid], v1 = xr[tid + 256], v2 = xr[tid + 512];
    float m1 = blk_sum(v0 + v1 + v2, sm) * (1.f / D_MODEL);
    v0 -= m1; v1 -= m1; v2 -= m1;
    float m2 = blk_sum(v0 + v1 + v2, sm) * (1.f / D_MODEL);
    v0 -= m2; v1 -= m2; v2 -= m2;
    float var = blk_sum(v0 * v0 + v1 * v1 + v2 * v2, sm) * (1.f / D_MODEL);
    float rms = sqrtf(var + 1e-6f);
    float k = fmaxf(rintf(log2f(rms)), 0.f);
    float inv = exp2f(-k);
    float g0 = gamma[tid], g1 = gamma[tid + 256], g2 = gamma[tid + 512];
    float h0 = v0 * inv * g0, h1 = v1 * inv * g1, h2 = v2 * inv * g2;
    float mx = blk_max(fmaxf(fabsf(h0), fmaxf(fabsf(h1), fabsf(h2))), sm);
    float sx = 127.f / (mx + 1e-6f);
    __hip_bfloat16* xo = xq + (size_t)row * D_MODEL;
    xo[tid]       = __float2bfloat16(rintf(clampf(h0 * sx, -128.f, 127.f)));
    xo[tid + 256] = __float2bfloat16(rintf(clampf(h1 * sx, -128.f, 127.f)));
    xo[tid + 512] = __float2bfloat16(rintf(clampf(h2 * sx, -128.f, 127.f)));
    if (tid == 0) s1[row] = swp[0] * (mx + 1e-6f) / 127.f;
}

// ---------------- generic row-wise |max| + act quant (f32 out) ----------------
__global__ void rowmax_quant(const float* __restrict__ in, int instride, int K,
                             const float* __restrict__ swp,
                             float* __restrict__ xq, float* __restrict__ sout) {
    int row = blockIdx.x, tid = threadIdx.x;
    const float* ir = in + (size_t)row * instride;
    __shared__ float sm[4];
    float mx = 0.f;
    for (int k = tid; k < K; k += 256) mx = fmaxf(mx, fabsf(ir[k]));
    mx = blk_max(mx, sm);
    float sx = 127.f / (mx + 1e-6f);
    for (int k = tid; k < K; k += 256)
        xq[(size_t)row * K + k] = rintf(clampf(ir[k] * sx, -128.f, 127.f));
    if (tid == 0) sout[row] = swp[0] * (mx + 1e-6f) / 127.f;
}
// ---------------- row-wise |max| + act quant (bf16 out) ----------------
__global__ void rowmax_quant_bf16(const float* __restrict__ in, int K,
                                  const float* __restrict__ swp,
                                  __hip_bfloat16* __restrict__ xq, float* __restrict__ sout) {
    int row = blockIdx.x, tid = threadIdx.x;
    const float* ir = in + (size_t)row * K;
    __shared__ float sm[4];
    float mx = 0.f;
    for (int k = tid; k < K; k += 256) mx = fmaxf(mx, fabsf(ir[k]));
    mx = blk_max(mx, sm);
    float sx = 127.f / (mx + 1e-6f);
    for (int k = tid; k < K; k += 256)
        xq[(size_t)row * K + k] = __float2bfloat16(rintf(clampf(ir[k] * sx, -128.f, 127.f)));
    if (tid == 0) sout[row] = swp[0] * (mx + 1e-6f) / 127.f;
}

// ---------------- MFMA bf16 GEMM: C[M,N] = (A[M,K] @ W[N,K]^T) * s[row] (+resid) ----------------
// m97 structure: global_load_lds(16B) staging, single buffer, 2 barriers/K-step.
// 4 waves in 2x2, each owns MF x NF 16x16 frags. BM=MF*32, BN=NF*32.
template<int MF, int NF>
__global__ __launch_bounds__(256) void gemm_mfma(
    const __hip_bfloat16* __restrict__ A, const __hip_bfloat16* __restrict__ W,
    const float* __restrict__ s, float* __restrict__ C,
    int M, int N, int K,
    const float* __restrict__ resid, const float* __restrict__ rg) {
    constexpr int BM = MF * 32, BN = NF * 32;
    __shared__ __hip_bfloat16 smA[BM * 32];
    __shared__ __hip_bfloat16 smB[BN * 32];
    const int tid = threadIdx.x;
    const int w = tid >> 6, lane = tid & 63;
    const int bm = blockIdx.y * BM, bn = blockIdx.x * BN;
    const int wr = (w >> 1) * (MF * 16), wc = (w & 1) * (NF * 16);
    const int fr = lane & 15, fq = lane >> 4;
    const int srow = lane >> 2;          // staging row within 16-row slab
    const int scol = (lane & 3) * 8;     // staging element col

    f32x4 acc[MF][NF];
    #pragma unroll
    for (int i = 0; i < MF; ++i)
        #pragma unroll
        for (int j = 0; j < NF; ++j)
            acc[i][j] = (f32x4){0.f, 0.f, 0.f, 0.f};

    for (int k0 = 0; k0 < K; k0 += 32) {
        #pragma unroll
        for (int q = 0; q < BM / 64; ++q) {
            int rr = (w * (BM / 64) + q) * 16;
            gload_lds16(A + (size_t)(bm + rr + srow) * K + k0 + scol, &smA[rr * 32]);
        }
        #pragma unroll
        for (int q = 0; q < BN / 64; ++q) {
            int rr = (w * (BN / 64) + q) * 16;
            gload_lds16(W + (size_t)(bn + rr + srow) * K + k0 + scol, &smB[rr * 32]);
        }
        __syncthreads();
        sh8 af[MF], bfr[NF];
        #pragma unroll
        for (int i = 0; i < MF; ++i)
            af[i] = *(const sh8*)&smA[(wr + i * 16 + fr) * 32 + fq * 8];
        #pragma unroll
        for (int j = 0; j < NF; ++j)
            bfr[j] = *(const sh8*)&smB[(wc + j * 16 + fr) * 32 + fq * 8];
        #pragma unroll
        for (int i = 0; i < MF; ++i)
            #pragma unroll
            for (int j = 0; j < NF; ++j)
                acc[i][j] = __builtin_amdgcn_mfma_f32_16x16x32_bf16(af[i], bfr[j], acc[i][j], 0, 0, 0);
        __syncthreads();
    }
    const float rgv = resid ? rg[0] : 0.f;
    #pragma unroll
    for (int i = 0; i < MF; ++i) {
        #pragma unroll
        for (int q = 0; q < 4; ++q) {
            int r = bm + wr + i * 16 + fq * 4 + q;
            float sc = s[r];
            #pragma unroll
            for (int j = 0; j < NF; ++j) {
                int col = bn + wc + j * 16 + fr;
                float v = acc[i][j][q] * sc;
                size_t o = (size_t)r * N + col;
                if (resid) v = resid[o] + v * rgv;
                C[o] = v;
            }
        }
    }
}

// ---------------- VALU GEMM (kept for dt_proj, K=48) ----------------
__global__ __launch_bounds__(256) void gemm_rowscale(
    const float* __restrict__ A, const float* __restrict__ W,
    const float* __restrict__ s, float* __restrict__ C,
    int M, int N, int K,
    const float* __restrict__ resid, const float* __restrict__ rg) {
    __shared__ float As[16][68];
    __shared__ float Ws[16][68];
    int bm = blockIdx.y * 64, bn = blockIdx.x * 64;
    int tid = threadIdx.x;
    int tx = tid & 15, ty = tid >> 4;
    float acc[4][4] = {};
    for (int k0 = 0; k0 < K; k0 += 16) {
        int idx = tid;
        #pragma unroll
        for (int u = 0; u < 4; ++u, idx += 256) {
            int r = idx >> 4, c = idx & 15;
            As[c][r] = A[(size_t)(bm + r) * K + k0 + c];
            Ws[c][r] = W[(size_t)(bn + r) * K + k0 + c];
        }
        __syncthreads();
        #pragma unroll
        for (int kk = 0; kk < 16; ++kk) {
            float a0 = As[kk][ty * 4 + 0], a1 = As[kk][ty * 4 + 1];
            float a2 = As[kk][ty * 4 + 2], a3 = As[kk][ty * 4 + 3];
            float w0 = Ws[kk][tx * 4 + 0], w1 = Ws[kk][tx * 4 + 1];
            float w2 = Ws[kk][tx * 4 + 2], w3 = Ws[kk][tx * 4 + 3];
            acc[0][0] = fmaf(a0, w0, acc[0][0]); acc[0][1] = fmaf(a0, w1, acc[0][1]);
            acc[0][2] = fmaf(a0, w2, acc[0][2]); acc[0][3] = fmaf(a0, w3, acc[0][3]);
            acc[1][0] = fmaf(a1, w0, acc[1][0]); acc[1][1] = fmaf(a1, w1, acc[1][1]);
            acc[1][2] = fmaf(a1, w2, acc[1][2]); acc[1][3] = fmaf(a1, w3, acc[1][3]);
            acc[2][0] = fmaf(a2, w0, acc[2][0]); acc[2][1] = fmaf(a2, w1, acc[2][1]);
            acc[2][2] = fmaf(a2, w2, acc[2][2]); acc[2][3] = fmaf(a2, w3, acc[2][3]);
            acc[3][0] = fmaf(a3, w0, acc[3][0]); acc[3][1] = fmaf(a3, w1, acc[3][1]);
            acc[3][2] = fmaf(a3, w2, acc[3][2]); acc[3][3] = fmaf(a3, w3, acc[3][3]);
        }
        __syncthreads();
    }
    int row0 = bm + ty * 4, col0 = bn + tx * 4;
    #pragma unroll
    for (int i = 0; i < 4; ++i) {
        float sc = s[row0 + i];
        #pragma unroll
        for (int j = 0; j < 4; ++j) {
            float v = acc[i][j] * sc;
            size_t o = (size_t)(row0 + i) * N + col0 + j;
            if (resid) v = resid[o] + v * rg[0];
            C[o] = v;
        }
    }
}

// ---------------- depthwise causal conv(4) + clip + smooth softplus ----------------
__global__ void conv_softplus(const float* __restrict__ xz, const float* __restrict__ cw,
                              const float* __restrict__ cb, float* __restrict__ xs) {
    int idx = blockIdx.x * 256 + threadIdx.x;
    if (idx >= Bb * Ll * D_INNER) return;
    int c = idx % D_INNER;
    int l = (idx / D_INNER) % Ll;
    int b = idx / (D_INNER * Ll);
    float acc = cb[c];
    #pragma unroll
    for (int k = 0; k < 4; ++k) {
        int t = l - 3 + k;
        if (t >= 0)
            acc = fmaf(cw[c * 4 + k], xz[((size_t)(b * Ll + t)) * XZ_DIM + c], acc);
    }
    acc = clampf(acc, -50.f, 50.f);
    xs[idx] = 0.5f * (acc + sqrtf(fmaf(acc, acc, 4.f)));
}

// ---------------- small GEMM: proj[2048,80] = (xq2 @ wqT) * s2 ----------------
__global__ __launch_bounds__(256) void gemm_row80(
    const float* __restrict__ xq, const float* __restrict__ wT,
    const float* __restrict__ s, float* __restrict__ proj) {
    int row = blockIdx.x, tid = threadIdx.x;
    __shared__ float a[D_INNER];
    for (int k = tid; k < D_INNER; k += 256) a[k] = xq[(size_t)row * D_INNER + k];
    __syncthreads();
    if (tid < PROJ_DIM) {
        float acc = 0.f;
        for (int k = 0; k < D_INNER; ++k)
            acc = fmaf(a[k], wT[k * PROJ_DIM + tid], acc);
        proj[row * PROJ_DIM + tid] = acc * s[row];
    }
}

// ---------------- prep: dtv/xdt compute + LDS-tiled transpose to [d][b][l] ----------------
__global__ __launch_bounds__(256) void prep_transpose(
    const float* __restrict__ dmod, const float* __restrict__ xs,
    float* __restrict__ dmT, float* __restrict__ xdtT) {
    __shared__ float t0[64][65];
    __shared__ float t1[64][65];
    int r0 = blockIdx.y * 64;   // row tile (within [0,2048))
    int d0 = blockIdx.x * 64;   // col tile (within [0,1536))
    int tid = threadIdx.x;
    #pragma unroll
    for (int i = 0; i < 16; ++i) {
        int idx = tid + i * 256;
        int rr = idx >> 6, cc = idx & 63;
        size_t src = (size_t)(r0 + rr) * D_INNER + d0 + cc;
        float dm = dmod[src];
        float xv = xs[src];
        float dtv = clampf(0.5f * (dm + sqrtf(fmaf(dm, dm, 4.f))) * 0.01f, 0.f, 0.1f);
        t0[cc][rr] = dm;
        t1[cc][rr] = xv * dtv;
    }
    __syncthreads();
    int b = r0 >> 10;
    int lbase = r0 & 1023;
    #pragma unroll
    for (int i = 0; i < 16; ++i) {
        int idx = tid + i * 256;
        int dd = idx >> 6, ll = idx & 63;
        size_t dst = (size_t)((d0 + dd) * Bb + b) * Ll + lbase + ll;
        dmT[dst]  = t0[dd][ll];
        xdtT[dst] = t1[dd][ll];
    }
}

// ---------------- chunked parallel scan + C-contraction + z gate ----------------
#define NCHUNK 32
#define CLEN   32   // NCHUNK*CLEN == Ll
__global__ __launch_bounds__(512) void scan_chunked(
    const float* __restrict__ dmT, const float* __restrict__ xdtT,
    const float* __restrict__ proj, const float* __restrict__ xz,
    const float* __restrict__ base, const float* __restrict__ shifts,
    float* __restrict__ yg) {
    int bid = blockIdx.x;          // 0..Bb*D_INNER-1
    int d = bid >> 1, b = bid & 1;
    int tid = threadIdx.x;
    int chunk = tid >> 4, n = tid & 15;
    __shared__ float dmL[Ll];
    __shared__ float xdtL[Ll];
    __shared__ float Ps[NCHUNK][16];
    __shared__ float Hs[NCHUNK][16];
    __shared__ float Cin[NCHUNK][16];
    size_t tbase = (size_t)bid * Ll;   // (d*2+b)*1024
    for (int i = tid; i < Ll; i += 512) {
        dmL[i]  = dmT[tbase + i];
        xdtL[i] = xdtT[tbase + i];
    }
    float bs_n  = base[d * D_STATE + n];
    float asc_n = exp2f(-shifts[d * D_STATE + n]);
    __syncthreads();
    // pass A: local scan from 0, record (prod a, h_end)
    float P = 1.f, h = 0.f;
    int l0 = chunk * CLEN;
    const float* projR = proj + (size_t)(b * Ll) * PROJ_DIM;
    for (int s = 0; s < CLEN; ++s) {
        int l = l0 + s;
        float dm = dmL[l], xdt = xdtL[l];
        float Bv = projR[(size_t)l * PROJ_DIM + DT_RANK + n];
        float u = clampf(xdt * Bv, -100.f, 100.f);
        float a = clampf(bs_n + dm, 0.f, 32000.f) * asc_n;
        h = fmaf(a, h, u);
        P *= a;
    }
    Ps[chunk][n] = P;
    Hs[chunk][n] = h;
    __syncthreads();
    // mid-scan over chunk summaries (serial, 16 threads)
    if (tid < 16) {
        float carry = 0.f;
        for (int c = 0; c < NCHUNK; ++c) {
            Cin[c][tid] = carry;
            carry = fmaf(Ps[c][tid], carry, Hs[c][tid]);
        }
    }
    __syncthreads();
    // pass C: re-scan with carry-in, fused y = sum_n clip(h)*C, gate, store
    h = Cin[chunk][n];
    for (int s = 0; s < CLEN; ++s) {
        int l = l0 + s;
        float dm = dmL[l], xdt = xdtL[l];
        size_t pr = (size_t)l * PROJ_DIM;
        float Bv = projR[pr + DT_RANK + n];
        float Cv = projR[pr + DT_RANK + D_STATE + n];
        float u = clampf(xdt * Bv, -100.f, 100.f);
        float a = clampf(bs_n + dm, 0.f, 32000.f) * asc_n;
        h = fmaf(a, h, u);
        float hc = clampf(h, -1000.f, 1000.f);
        float y = hc * Cv;
        y += __shfl_xor(y, 1);
        y += __shfl_xor(y, 2);
        y += __shfl_xor(y, 4);
        y += __shfl_xor(y, 8);
        if (n == 0) {
            size_t r = (size_t)b * Ll + l;
            float z = xz[r * XZ_DIM + D_INNER + d];
            float g = 0.5f * (z / sqrtf(fmaf(z, z, 1.f)) + 1.f);
            yg[r * D_INNER + d] = y * g;
        }
    }
}

// ---------------- launcher ----------------
extern "C" void kernel_launch(void* const* d_in, const int* in_sizes, int n_in,
                              void* d_out, int out_size, void* d_ws, size_t ws_size,
                              hipStream_t stream) {
    const float* hs    = (const float*)d_in[0];
    const float* gamma = (const float*)d_in[1];
    const float* w_in  = (const float*)d_in[2];
    const float* cw    = (const float*)d_in[3];
    const float* cb    = (const float*)d_in[4];
    const float* w_xp  = (const float*)d_in[5];
    const float* w_dt  = (const float*)d_in[6];
    const float* w_out = (const float*)d_in[7];
    const float* base  = (const float*)d_in[8];
    const float* rg    = (const float*)d_in[9];
    const float* shifts= (const float*)d_in[10];
    float* ws  = (float*)d_ws;
    float* out = (float*)d_out;

    const int n_in_w = XZ_DIM * D_MODEL;      // 2359296
    const int n_xp_w = PROJ_DIM * D_INNER;    // 122880
    const int n_dt_w = D_INNER * DT_RANK;     // 73728
    const int n_out_w = D_MODEL * D_INNER;    // 1179648

    __hip_bfloat16* wqin  = (__hip_bfloat16*)(ws + OFF_WQIN);
    __hip_bfloat16* wqout = (__hip_bfloat16*)(ws + OFF_WQOUT);
    __hip_bfloat16* xq1   = (__hip_bfloat16*)(ws + OFF_XQ1);
    __hip_bfloat16* xq4   = (__hip_bfloat16*)(ws + OFF_XQ4);

    // 1. weight scales
    absmean_partial<<<64, 256, 0, stream>>>(w_in,  n_in_w,  ws + OFF_PART + 0);
    absmean_partial<<<64, 256, 0, stream>>>(w_xp,  n_xp_w,  ws + OFF_PART + 64);
    absmean_partial<<<64, 256, 0, stream>>>(w_dt,  n_dt_w,  ws + OFF_PART + 128);
    absmean_partial<<<64, 256, 0, stream>>>(w_out, n_out_w, ws + OFF_PART + 192);
    absmean_final<<<1, 64, 0, stream>>>(ws + OFF_PART, ws + OFF_SW,
                                        n_in_w, n_xp_w, n_dt_w, n_out_w);
    // 2. ternary weights (bf16 for MFMA GEMMs, f32 for VALU paths)
    quant_w_bf16<<<(n_in_w + 255) / 256, 256, 0, stream>>>(w_in,  ws + OFF_SW + 0, wqin, n_in_w);
    quant_w_T   <<<(n_xp_w + 255) / 256, 256, 0, stream>>>(w_xp,  ws + OFF_SW + 1, ws + OFF_WQXPT);
    quant_w     <<<(n_dt_w + 255) / 256, 256, 0, stream>>>(w_dt,  ws + OFF_SW + 2, ws + OFF_WQDT, n_dt_w);
    quant_w_bf16<<<(n_out_w + 255) / 256, 256, 0, stream>>>(w_out, ws + OFF_SW + 3, wqout, n_out_w);
    // 3. norm + act quant (bf16)
    norm_quant<<<ROWS, 256, 0, stream>>>(hs, gamma, ws + OFF_SW + 0, xq1, ws + OFF_S1);
    // 4. in_proj MFMA GEMM -> xz (f32)
    gemm_mfma<4, 4><<<dim3(XZ_DIM / 128, ROWS / 128), 256, 0, stream>>>(
        xq1, wqin, ws + OFF_S1, ws + OFF_XZ,
        ROWS, XZ_DIM, D_MODEL, nullptr, nullptr);
    // 5. conv + softplus
    conv_softplus<<<(Bb * Ll * D_INNER + 255) / 256, 256, 0, stream>>>(
        ws + OFF_XZ, cw, cb, ws + OFF_XS);
    // 6. quant for x_proj
    rowmax_quant<<<ROWS, 256, 0, stream>>>(ws + OFF_XS, D_INNER, D_INNER,
                                           ws + OFF_SW + 1, ws + OFF_XQ2, ws + OFF_S2);
    // 7. x_proj GEMM -> proj[2048,80]
    gemm_row80<<<ROWS, 256, 0, stream>>>(ws + OFF_XQ2, ws + OFF_WQXPT, ws + OFF_S2, ws + OFF_PROJ);
    // 8. dt quant (first 48 cols of proj)
    rowmax_quant<<<ROWS, 256, 0, stream>>>(ws + OFF_PROJ, PROJ_DIM, DT_RANK,
                                           ws + OFF_SW + 2, ws + OFF_XQ3, ws + OFF_S3);
    // 9. dt_proj GEMM -> decay_mod (VALU, K=48 tiny)
    gemm_rowscale<<<dim3(D_INNER / 64, ROWS / 64), 256, 0, stream>>>(
        ws + OFF_XQ3, ws + OFF_WQDT, ws + OFF_S3, ws + OFF_DMOD,
        ROWS, D_INNER, DT_RANK, nullptr, nullptr);
    // 10a. prep: dtv/xdt + transpose to [d][b][l] (reuse XQ4 for dmT, XQ2 for xdtT)
    prep_transpose<<<dim3(D_INNER / 64, ROWS / 64), 256, 0, stream>>>(
        ws + OFF_DMOD, ws + OFF_XS, ws + OFF_XQ4, ws + OFF_XQ2);
    // 10b. chunked scan + gate
    scan_chunked<<<Bb * D_INNER, 512, 0, stream>>>(
        ws + OFF_XQ4, ws + OFF_XQ2, ws + OFF_PROJ, ws + OFF_XZ, base, shifts, ws + OFF_YG);
    // 11. quant for out_proj (bf16; overwrites dmT region — scan already done)
    rowmax_quant_bf16<<<ROWS, 256, 0, stream>>>(ws + OFF_YG, D_INNER,
                                                ws + OFF_SW + 3, xq4, ws + OFF_S4);
    // 12. out_proj MFMA GEMM + residual epilogue -> d_out
    gemm_mfma<2, 4><<<dim3(D_MODEL / 128, ROWS / 64), 256, 0, stream>>>(
        xq4, wqout, ws + OFF_S4, out,
        ROWS, D_MODEL, D_INNER, hs, rg);
}

// Round 4
// 342.408 us; speedup vs baseline: 6.6000x; 1.0074x over previous
//
#include <hip/hip_runtime.h>
#include <hip/hip_bf16.h>
#include <math.h>

// ---------------- problem constants ----------------
#define D_MODEL 768
#define D_STATE 16
#define DT_RANK 48
#define D_INNER 1536           // 2*D_MODEL
#define XZ_DIM  3072           // 2*D_INNER
#define PROJ_DIM 80            // DT_RANK + 2*D_STATE
#define Bb 2
#define Ll 1024
#define ROWS (Bb*Ll)           // 2048

// ---------------- ws layout (float offsets; bf16 buffers reuse same regions) ----------------
#define OFF_PART   0u                     // 128 partials (64 in / 16 xp / 16 dt / 32 out)
#define OFF_SW     256u                   // 4 scalars
#define OFF_WQIN   512u                   // bf16 [3072][768]
#define OFF_WQXPT  (OFF_WQIN  + 2359296u) // f32 [1536][80] (transposed)
#define OFF_WQDT   (OFF_WQXPT + 122880u)  // f32 [1536][48]
#define OFF_WQOUT  (OFF_WQDT  + 73728u)   // bf16 [768][1536]
#define OFF_XQ1    (OFF_WQOUT + 1179648u) // bf16 [2048][768]
#define OFF_S1     (OFF_XQ1   + 1572864u) // 2048
#define OFF_XZ     (OFF_S1    + 2048u)    // f32 [2048][3072]
#define OFF_XS     (OFF_XZ    + 6291456u) // f32 [2048][1536]
#define OFF_XQ2    (OFF_XS    + 3145728u) // f32 2048x1536 (later reused as xdtT [1536][2][1024])
#define OFF_S2     (OFF_XQ2   + 3145728u) // 2048
#define OFF_PROJ   (OFF_S2    + 2048u)    // 2048x80
#define OFF_XQ3    (OFF_PROJ  + 163840u)  // f32 [2048][48]
#define OFF_S3     (OFF_XQ3   + 98304u)   // 2048
#define OFF_DMOD   (OFF_S3    + 2048u)    // f32 [2048][1536]
#define OFF_YG     (OFF_DMOD  + 3145728u) // f32 [2048][1536]
#define OFF_XQ4    (OFF_YG    + 3145728u) // dmT f32 [1536][2][1024], then bf16 [2048][1536]
#define OFF_S4     (OFF_XQ4   + 3145728u) // 2048

typedef short sh8 __attribute__((ext_vector_type(8)));
typedef float f32x4 __attribute__((ext_vector_type(4)));

#define N_IN_W  (XZ_DIM * D_MODEL)     // 2359296
#define N_XP_W  (PROJ_DIM * D_INNER)   // 122880
#define N_DT_W  (D_INNER * DT_RANK)    // 73728
#define N_OUT_W (D_MODEL * D_INNER)    // 1179648

// ---------------- helpers ----------------
__device__ __forceinline__ float blk_sum(float v, float* sm) {
    int tid = threadIdx.x;
    #pragma unroll
    for (int off = 32; off; off >>= 1) v += __shfl_down(v, off);
    __syncthreads();
    if ((tid & 63) == 0) sm[tid >> 6] = v;
    __syncthreads();
    return (sm[0] + sm[1]) + (sm[2] + sm[3]);
}
__device__ __forceinline__ float blk_max(float v, float* sm) {
    int tid = threadIdx.x;
    #pragma unroll
    for (int off = 32; off; off >>= 1) v = fmaxf(v, __shfl_down(v, off));
    __syncthreads();
    if ((tid & 63) == 0) sm[tid >> 6] = v;
    __syncthreads();
    return fmaxf(fmaxf(sm[0], sm[1]), fmaxf(sm[2], sm[3]));
}
__device__ __forceinline__ float clampf(float v, float lo, float hi) {
    return fminf(fmaxf(v, lo), hi);
}
__device__ __forceinline__ void gload_lds16(const __hip_bfloat16* g, __hip_bfloat16* l) {
    __builtin_amdgcn_global_load_lds(
        (const __attribute__((address_space(1))) void*)g,
        (__attribute__((address_space(3))) void*)l, 16, 0, 0);
}

// ---------------- weight absmean: all 4 matrices in one launch ----------------
__global__ void absmean_all(const float* __restrict__ w0, const float* __restrict__ w1,
                            const float* __restrict__ w2, const float* __restrict__ w3,
                            float* __restrict__ part) {
    __shared__ float sm[4];
    int bid = blockIdx.x;
    const float* w; int n, sub, nb;
    if (bid < 64)      { w = w0; n = N_IN_W;  sub = bid;      nb = 64; }
    else if (bid < 80) { w = w1; n = N_XP_W;  sub = bid - 64; nb = 16; }
    else if (bid < 96) { w = w2; n = N_DT_W;  sub = bid - 80; nb = 16; }
    else               { w = w3; n = N_OUT_W; sub = bid - 96; nb = 32; }
    float sum = 0.f;
    for (int i = sub * 256 + threadIdx.x; i < n; i += nb * 256)
        sum += fabsf(w[i]);
    sum = blk_sum(sum, sm);
    if (threadIdx.x == 0) part[bid] = sum;
}

__global__ void absmean_final4(const float* __restrict__ part, float* __restrict__ sw) {
    int tid = threadIdx.x;  // 64 threads
    const int cnt[4] = {64, 16, 16, 32};
    const int off[4] = {0, 64, 80, 96};
    const int ns[4]  = {N_IN_W, N_XP_W, N_DT_W, N_OUT_W};
    #pragma unroll
    for (int m = 0; m < 4; ++m) {
        float v = (tid < cnt[m]) ? part[off[m] + tid] : 0.f;
        #pragma unroll
        for (int o = 32; o; o >>= 1) v += __shfl_down(v, o);
        if (tid == 0) sw[m] = v / (float)ns[m] + 1e-6f;
    }
}

// ---------------- all 4 weight quantizations in one launch ----------------
__global__ void quant_all(const float* __restrict__ w_in, const float* __restrict__ w_xp,
                          const float* __restrict__ w_dt, const float* __restrict__ w_out,
                          const float* __restrict__ sw,
                          __hip_bfloat16* __restrict__ wqin, float* __restrict__ wqxpT,
                          float* __restrict__ wqdt, __hip_bfloat16* __restrict__ wqout) {
    int idx = blockIdx.x * 256 + threadIdx.x;
    if (idx < N_IN_W) {
        float v = rintf(clampf(w_in[idx] / sw[0], -1.f, 1.f));
        wqin[idx] = __float2bfloat16(v);
    } else if (idx < N_IN_W + N_XP_W) {
        int i = idx - N_IN_W;
        int j = i / D_INNER, k = i % D_INNER;
        wqxpT[k * PROJ_DIM + j] = rintf(clampf(w_xp[i] / sw[1], -1.f, 1.f));
    } else if (idx < N_IN_W + N_XP_W + N_DT_W) {
        int i = idx - N_IN_W - N_XP_W;
        wqdt[i] = rintf(clampf(w_dt[i] / sw[2], -1.f, 1.f));
    } else if (idx < N_IN_W + N_XP_W + N_DT_W + N_OUT_W) {
        int i = idx - N_IN_W - N_XP_W - N_DT_W;
        float v = rintf(clampf(w_out[i] / sw[3], -1.f, 1.f));
        wqout[i] = __float2bfloat16(v);
    }
}

// ---------------- fused center x2 + bitshift-norm + act quant (bf16 out) ----------------
__global__ __launch_bounds__(256) void norm_quant(
    const float* __restrict__ x, const float* __restrict__ gamma,
    const float* __restrict__ swp, __hip_bfloat16* __restrict__ xq, float* __restrict__ s1) {
    int row = blockIdx.x, tid = threadIdx.x;
    const float* xr = x + (size_t)row * D_MODEL;
    __shared__ float sm[4];
    float v0 = xr[tid], v1 = xr[tid + 256], v2 = xr[tid + 512];
    float m1 = blk_sum(v0 + v1 + v2, sm) * (1.f / D_MODEL);
    v0 -= m1; v1 -= m1; v2 -= m1;
    float m2 = blk_sum(v0 + v1 + v2, sm) * (1.f / D_MODEL);
    v0 -= m2; v1 -= m2; v2 -= m2;
    float var = blk_sum(v0 * v0 + v1 * v1 + v2 * v2, sm) * (1.f / D_MODEL);
    float rms = sqrtf(var + 1e-6f);
    float k = fmaxf(rintf(log2f(rms)), 0.f);
    float inv = exp2f(-k);
    float g0 = gamma[tid], g1 = gamma[tid + 256], g2 = gamma[tid + 512];
    float h0 = v0 * inv * g0, h1 = v1 * inv * g1, h2 = v2 * inv * g2;
    float mx = blk_max(fmaxf(fabsf(h0), fmaxf(fabsf(h1), fabsf(h2))), sm);
    float sx = 127.f / (mx + 1e-6f);
    __hip_bfloat16* xo = xq + (size_t)row * D_MODEL;
    xo[tid]       = __float2bfloat16(rintf(clampf(h0 * sx, -128.f, 127.f)));
    xo[tid + 256] = __float2bfloat16(rintf(clampf(h1 * sx, -128.f, 127.f)));
    xo[tid + 512] = __float2bfloat16(rintf(clampf(h2 * sx, -128.f, 127.f)));
    if (tid == 0) s1[row] = swp[0] * (mx + 1e-6f) / 127.f;
}

// ---------------- generic row-wise |max| + act quant (f32 out) ----------------
__global__ void rowmax_quant(const float* __restrict__ in, int instride, int K,
                             const float* __restrict__ swp,
                             float* __restrict__ xq, float* __restrict__ sout) {
    int row = blockIdx.x, tid = threadIdx.x;
    const float* ir = in + (size_t)row * instride;
    __shared__ float sm[4];
    float mx = 0.f;
    for (int k = tid; k < K; k += 256) mx = fmaxf(mx, fabsf(ir[k]));
    mx = blk_max(mx, sm);
    float sx = 127.f / (mx + 1e-6f);
    for (int k = tid; k < K; k += 256)
        xq[(size_t)row * K + k] = rintf(clampf(ir[k] * sx, -128.f, 127.f));
    if (tid == 0) sout[row] = swp[0] * (mx + 1e-6f) / 127.f;
}
// ---------------- row-wise |max| + act quant (bf16 out) ----------------
__global__ void rowmax_quant_bf16(const float* __restrict__ in, int K,
                                  const float* __restrict__ swp,
                                  __hip_bfloat16* __restrict__ xq, float* __restrict__ sout) {
    int row = blockIdx.x, tid = threadIdx.x;
    const float* ir = in + (size_t)row * K;
    __shared__ float sm[4];
    float mx = 0.f;
    for (int k = tid; k < K; k += 256) mx = fmaxf(mx, fabsf(ir[k]));
    mx = blk_max(mx, sm);
    float sx = 127.f / (mx + 1e-6f);
    for (int k = tid; k < K; k += 256)
        xq[(size_t)row * K + k] = __float2bfloat16(rintf(clampf(ir[k] * sx, -128.f, 127.f)));
    if (tid == 0) sout[row] = swp[0] * (mx + 1e-6f) / 127.f;
}

// ---------------- MFMA bf16 GEMM: C[M,N] = (A[M,K] @ W[N,K]^T) * s[row] (+resid) ----------------
template<int MF, int NF>
__global__ __launch_bounds__(256) void gemm_mfma(
    const __hip_bfloat16* __restrict__ A, const __hip_bfloat16* __restrict__ W,
    const float* __restrict__ s, float* __restrict__ C,
    int M, int N, int K,
    const float* __restrict__ resid, const float* __restrict__ rg) {
    constexpr int BM = MF * 32, BN = NF * 32;
    __shared__ __hip_bfloat16 smA[BM * 32];
    __shared__ __hip_bfloat16 smB[BN * 32];
    const int tid = threadIdx.x;
    const int w = tid >> 6, lane = tid & 63;
    const int bm = blockIdx.y * BM, bn = blockIdx.x * BN;
    const int wr = (w >> 1) * (MF * 16), wc = (w & 1) * (NF * 16);
    const int fr = lane & 15, fq = lane >> 4;
    const int srow = lane >> 2;
    const int scol = (lane & 3) * 8;

    f32x4 acc[MF][NF];
    #pragma unroll
    for (int i = 0; i < MF; ++i)
        #pragma unroll
        for (int j = 0; j < NF; ++j)
            acc[i][j] = (f32x4){0.f, 0.f, 0.f, 0.f};

    for (int k0 = 0; k0 < K; k0 += 32) {
        #pragma unroll
        for (int q = 0; q < BM / 64; ++q) {
            int rr = (w * (BM / 64) + q) * 16;
            gload_lds16(A + (size_t)(bm + rr + srow) * K + k0 + scol, &smA[rr * 32]);
        }
        #pragma unroll
        for (int q = 0; q < BN / 64; ++q) {
            int rr = (w * (BN / 64) + q) * 16;
            gload_lds16(W + (size_t)(bn + rr + srow) * K + k0 + scol, &smB[rr * 32]);
        }
        __syncthreads();
        sh8 af[MF], bfr[NF];
        #pragma unroll
        for (int i = 0; i < MF; ++i)
            af[i] = *(const sh8*)&smA[(wr + i * 16 + fr) * 32 + fq * 8];
        #pragma unroll
        for (int j = 0; j < NF; ++j)
            bfr[j] = *(const sh8*)&smB[(wc + j * 16 + fr) * 32 + fq * 8];
        #pragma unroll
        for (int i = 0; i < MF; ++i)
            #pragma unroll
            for (int j = 0; j < NF; ++j)
                acc[i][j] = __builtin_amdgcn_mfma_f32_16x16x32_bf16(af[i], bfr[j], acc[i][j], 0, 0, 0);
        __syncthreads();
    }
    const float rgv = resid ? rg[0] : 0.f;
    #pragma unroll
    for (int i = 0; i < MF; ++i) {
        #pragma unroll
        for (int q = 0; q < 4; ++q) {
            int r = bm + wr + i * 16 + fq * 4 + q;
            float sc = s[r];
            #pragma unroll
            for (int j = 0; j < NF; ++j) {
                int col = bn + wc + j * 16 + fr;
                float v = acc[i][j][q] * sc;
                size_t o = (size_t)r * N + col;
                if (resid) v = resid[o] + v * rgv;
                C[o] = v;
            }
        }
    }
}

// ---------------- VALU GEMM (kept for dt_proj, K=48) ----------------
__global__ __launch_bounds__(256) void gemm_rowscale(
    const float* __restrict__ A, const float* __restrict__ W,
    const float* __restrict__ s, float* __restrict__ C,
    int M, int N, int K,
    const float* __restrict__ resid, const float* __restrict__ rg) {
    __shared__ float As[16][68];
    __shared__ float Ws[16][68];
    int bm = blockIdx.y * 64, bn = blockIdx.x * 64;
    int tid = threadIdx.x;
    int tx = tid & 15, ty = tid >> 4;
    float acc[4][4] = {};
    for (int k0 = 0; k0 < K; k0 += 16) {
        int idx = tid;
        #pragma unroll
        for (int u = 0; u < 4; ++u, idx += 256) {
            int r = idx >> 4, c = idx & 15;
            As[c][r] = A[(size_t)(bm + r) * K + k0 + c];
            Ws[c][r] = W[(size_t)(bn + r) * K + k0 + c];
        }
        __syncthreads();
        #pragma unroll
        for (int kk = 0; kk < 16; ++kk) {
            float a0 = As[kk][ty * 4 + 0], a1 = As[kk][ty * 4 + 1];
            float a2 = As[kk][ty * 4 + 2], a3 = As[kk][ty * 4 + 3];
            float w0 = Ws[kk][tx * 4 + 0], w1 = Ws[kk][tx * 4 + 1];
            float w2 = Ws[kk][tx * 4 + 2], w3 = Ws[kk][tx * 4 + 3];
            acc[0][0] = fmaf(a0, w0, acc[0][0]); acc[0][1] = fmaf(a0, w1, acc[0][1]);
            acc[0][2] = fmaf(a0, w2, acc[0][2]); acc[0][3] = fmaf(a0, w3, acc[0][3]);
            acc[1][0] = fmaf(a1, w0, acc[1][0]); acc[1][1] = fmaf(a1, w1, acc[1][1]);
            acc[1][2] = fmaf(a1, w2, acc[1][2]); acc[1][3] = fmaf(a1, w3, acc[1][3]);
            acc[2][0] = fmaf(a2, w0, acc[2][0]); acc[2][1] = fmaf(a2, w1, acc[2][1]);
            acc[2][2] = fmaf(a2, w2, acc[2][2]); acc[2][3] = fmaf(a2, w3, acc[2][3]);
            acc[3][0] = fmaf(a3, w0, acc[3][0]); acc[3][1] = fmaf(a3, w1, acc[3][1]);
            acc[3][2] = fmaf(a3, w2, acc[3][2]); acc[3][3] = fmaf(a3, w3, acc[3][3]);
        }
        __syncthreads();
    }
    int row0 = bm + ty * 4, col0 = bn + tx * 4;
    #pragma unroll
    for (int i = 0; i < 4; ++i) {
        float sc = s[row0 + i];
        #pragma unroll
        for (int j = 0; j < 4; ++j) {
            float v = acc[i][j] * sc;
            size_t o = (size_t)(row0 + i) * N + col0 + j;
            if (resid) v = resid[o] + v * rg[0];
            C[o] = v;
        }
    }
}

// ---------------- fused depthwise conv(4)+softplus + rowmax + quant ----------------
__global__ __launch_bounds__(256) void conv_quant(
    const float* __restrict__ xz, const float* __restrict__ cw, const float* __restrict__ cb,
    const float* __restrict__ swp, float* __restrict__ xs,
    float* __restrict__ xq2, float* __restrict__ s2) {
    int row = blockIdx.x, tid = threadIdx.x;
    int b = row >> 10, l = row & 1023;
    __shared__ float sm[4];
    float v[6];
    #pragma unroll
    for (int k = 0; k < 6; ++k) {
        int c = tid + k * 256;
        float acc = cb[c];
        #pragma unroll
        for (int t = 0; t < 4; ++t) {
            int tt = l - 3 + t;
            if (tt >= 0)
                acc = fmaf(cw[c * 4 + t], xz[(size_t)(b * Ll + tt) * XZ_DIM + c], acc);
        }
        acc = clampf(acc, -50.f, 50.f);
        v[k] = 0.5f * (acc + sqrtf(fmaf(acc, acc, 4.f)));
    }
    float mx = 0.f;
    #pragma unroll
    for (int k = 0; k < 6; ++k) mx = fmaxf(mx, fabsf(v[k]));
    mx = blk_max(mx, sm);
    float sx = 127.f / (mx + 1e-6f);
    #pragma unroll
    for (int k = 0; k < 6; ++k) {
        int c = tid + k * 256;
        xs[(size_t)row * D_INNER + c] = v[k];
        xq2[(size_t)row * D_INNER + c] = rintf(clampf(v[k] * sx, -128.f, 127.f));
    }
    if (tid == 0) s2[row] = swp[0] * (mx + 1e-6f) / 127.f;
}

// ---------------- small GEMM: proj[2048,80] = (xq2 @ wqT) * s2, 3-way K-split ----------------
__global__ __launch_bounds__(256) void gemm_row80(
    const float* __restrict__ xq, const float* __restrict__ wT,
    const float* __restrict__ s, float* __restrict__ proj) {
    int row = blockIdx.x, tid = threadIdx.x;
    __shared__ float a[D_INNER];
    __shared__ float psum[3][PROJ_DIM];
    for (int k = tid; k < D_INNER; k += 256) a[k] = xq[(size_t)row * D_INNER + k];
    __syncthreads();
    if (tid < 240) {
        int col = tid % PROJ_DIM, slice = tid / PROJ_DIM;
        int k0 = slice * 512, k1 = k0 + 512;
        float acc = 0.f;
        for (int k = k0; k < k1; ++k)
            acc = fmaf(a[k], wT[k * PROJ_DIM + col], acc);
        psum[slice][col] = acc;
    }
    __syncthreads();
    if (tid < PROJ_DIM)
        proj[row * PROJ_DIM + tid] = (psum[0][tid] + psum[1][tid] + psum[2][tid]) * s[row];
}

// ---------------- prep: dtv/xdt compute + LDS-tiled transpose to [d][b][l] ----------------
__global__ __launch_bounds__(256) void prep_transpose(
    const float* __restrict__ dmod, const float* __restrict__ xs,
    float* __restrict__ dmT, float* __restrict__ xdtT) {
    __shared__ float t0[64][65];
    __shared__ float t1[64][65];
    int r0 = blockIdx.y * 64;
    int d0 = blockIdx.x * 64;
    int tid = threadIdx.x;
    #pragma unroll
    for (int i = 0; i < 16; ++i) {
        int idx = tid + i * 256;
        int rr = idx >> 6, cc = idx & 63;
        size_t src = (size_t)(r0 + rr) * D_INNER + d0 + cc;
        float dm = dmod[src];
        float xv = xs[src];
        float dtv = clampf(0.5f * (dm + sqrtf(fmaf(dm, dm, 4.f))) * 0.01f, 0.f, 0.1f);
        t0[cc][rr] = dm;
        t1[cc][rr] = xv * dtv;
    }
    __syncthreads();
    int b = r0 >> 10;
    int lbase = r0 & 1023;
    #pragma unroll
    for (int i = 0; i < 16; ++i) {
        int idx = tid + i * 256;
        int dd = idx >> 6, ll = idx & 63;
        size_t dst = (size_t)((d0 + dd) * Bb + b) * Ll + lbase + ll;
        dmT[dst]  = t0[dd][ll];
        xdtT[dst] = t1[dd][ll];
    }
}

// ---------------- chunked parallel scan + C-contraction + z gate (v4) ----------------
// pass A caches a[s],u[s] in registers (fully unrolled -> static indexing);
// dm/xdt LDS padded (i + i/32) so chunk-stride reads are conflict-free.
#define NCHUNK 32
#define CLEN   32
#define PADIDX(i) ((i) + ((i) >> 5))
__global__ __launch_bounds__(512, 2) void scan_chunked(
    const float* __restrict__ dmT, const float* __restrict__ xdtT,
    const float* __restrict__ proj, const float* __restrict__ xz,
    const float* __restrict__ base, const float* __restrict__ shifts,
    float* __restrict__ yg) {
    int bid = blockIdx.x;          // 0..Bb*D_INNER-1
    int d = bid >> 1, b = bid & 1;
    int tid = threadIdx.x;
    int chunk = tid >> 4, n = tid & 15;
    __shared__ float dmL[Ll + Ll / 32];
    __shared__ float xdtL[Ll + Ll / 32];
    __shared__ float Ps[NCHUNK][16];
    __shared__ float Hs[NCHUNK][16];
    __shared__ float Cin[NCHUNK][16];
    size_t tbase = (size_t)bid * Ll;
    for (int i = tid; i < Ll; i += 512) {
        dmL[PADIDX(i)]  = dmT[tbase + i];
        xdtL[PADIDX(i)] = xdtT[tbase + i];
    }
    float bs_n  = base[d * D_STATE + n];
    float asc_n = exp2f(-shifts[d * D_STATE + n]);
    __syncthreads();
    // pass A: local scan from 0, caching a[s], u[s]
    float av[CLEN], uv[CLEN];
    float P = 1.f, h = 0.f;
    int l0 = chunk * CLEN;
    int pbase = PADIDX(l0);   // within chunk: l0+s -> pbase+s (no pad crossing, CLEN==32)
    const float* projR = proj + (size_t)(b * Ll) * PROJ_DIM;
    #pragma unroll
    for (int s = 0; s < CLEN; ++s) {
        float dm = dmL[pbase + s], xdt = xdtL[pbase + s];
        float Bv = projR[(size_t)(l0 + s) * PROJ_DIM + DT_RANK + n];
        float u = clampf(xdt * Bv, -100.f, 100.f);
        float a = clampf(bs_n + dm, 0.f, 32000.f) * asc_n;
        h = fmaf(a, h, u);
        P *= a;
        av[s] = a;
        uv[s] = u;
    }
    Ps[chunk][n] = P;
    Hs[chunk][n] = h;
    __syncthreads();
    // mid-scan over chunk summaries (serial, 16 threads)
    if (tid < 16) {
        float carry = 0.f;
        for (int c = 0; c < NCHUNK; ++c) {
            Cin[c][tid] = carry;
            carry = fmaf(Ps[c][tid], carry, Hs[c][tid]);
        }
    }
    __syncthreads();
    // pass C: replay from cached a,u with carry-in; fused y, gate, store
    h = Cin[chunk][n];
    #pragma unroll
    for (int s = 0; s < CLEN; ++s) {
        int l = l0 + s;
        float Cv = projR[(size_t)l * PROJ_DIM + DT_RANK + D_STATE + n];
        h = fmaf(av[s], h, uv[s]);
        float hc = clampf(h, -1000.f, 1000.f);
        float y = hc * Cv;
        y += __shfl_xor(y, 1);
        y += __shfl_xor(y, 2);
        y += __shfl_xor(y, 4);
        y += __shfl_xor(y, 8);
        if (n == 0) {
            size_t r = (size_t)b * Ll + l;
            float z = xz[r * XZ_DIM + D_INNER + d];
            float g = 0.5f * (z / sqrtf(fmaf(z, z, 1.f)) + 1.f);
            yg[r * D_INNER + d] = y * g;
        }
    }
}

// ---------------- launcher ----------------
extern "C" void kernel_launch(void* const* d_in, const int* in_sizes, int n_in,
                              void* d_out, int out_size, void* d_ws, size_t ws_size,
                              hipStream_t stream) {
    const float* hs    = (const float*)d_in[0];
    const float* gamma = (const float*)d_in[1];
    const float* w_in  = (const float*)d_in[2];
    const float* cw    = (const float*)d_in[3];
    const float* cb    = (const float*)d_in[4];
    const float* w_xp  = (const float*)d_in[5];
    const float* w_dt  = (const float*)d_in[6];
    const float* w_out = (const float*)d_in[7];
    const float* base  = (const float*)d_in[8];
    const float* rg    = (const float*)d_in[9];
    const float* shifts= (const float*)d_in[10];
    float* ws  = (float*)d_ws;
    float* out = (float*)d_out;

    __hip_bfloat16* wqin  = (__hip_bfloat16*)(ws + OFF_WQIN);
    __hip_bfloat16* wqout = (__hip_bfloat16*)(ws + OFF_WQOUT);
    __hip_bfloat16* xq1   = (__hip_bfloat16*)(ws + OFF_XQ1);
    __hip_bfloat16* xq4   = (__hip_bfloat16*)(ws + OFF_XQ4);

    // 1. weight scales (one launch + final)
    absmean_all<<<128, 256, 0, stream>>>(w_in, w_xp, w_dt, w_out, ws + OFF_PART);
    absmean_final4<<<1, 64, 0, stream>>>(ws + OFF_PART, ws + OFF_SW);
    // 2. ternary weights (one launch)
    const int n_tot = N_IN_W + N_XP_W + N_DT_W + N_OUT_W;
    quant_all<<<(n_tot + 255) / 256, 256, 0, stream>>>(
        w_in, w_xp, w_dt, w_out, ws + OFF_SW,
        wqin, ws + OFF_WQXPT, ws + OFF_WQDT, wqout);
    // 3. norm + act quant (bf16)
    norm_quant<<<ROWS, 256, 0, stream>>>(hs, gamma, ws + OFF_SW + 0, xq1, ws + OFF_S1);
    // 4. in_proj MFMA GEMM -> xz
    gemm_mfma<4, 4><<<dim3(XZ_DIM / 128, ROWS / 128), 256, 0, stream>>>(
        xq1, wqin, ws + OFF_S1, ws + OFF_XZ,
        ROWS, XZ_DIM, D_MODEL, nullptr, nullptr);
    // 5+6. fused conv + softplus + rowmax + quant
    conv_quant<<<ROWS, 256, 0, stream>>>(ws + OFF_XZ, cw, cb, ws + OFF_SW + 1,
                                         ws + OFF_XS, ws + OFF_XQ2, ws + OFF_S2);
    // 7. x_proj GEMM -> proj[2048,80]
    gemm_row80<<<ROWS, 256, 0, stream>>>(ws + OFF_XQ2, ws + OFF_WQXPT, ws + OFF_S2, ws + OFF_PROJ);
    // 8. dt quant (first 48 cols of proj)
    rowmax_quant<<<ROWS, 256, 0, stream>>>(ws + OFF_PROJ, PROJ_DIM, DT_RANK,
                                           ws + OFF_SW + 2, ws + OFF_XQ3, ws + OFF_S3);
    // 9. dt_proj GEMM -> decay_mod (VALU, K=48)
    gemm_rowscale<<<dim3(D_INNER / 64, ROWS / 64), 256, 0, stream>>>(
        ws + OFF_XQ3, ws + OFF_WQDT, ws + OFF_S3, ws + OFF_DMOD,
        ROWS, D_INNER, DT_RANK, nullptr, nullptr);
    // 10a. prep: dtv/xdt + transpose (XQ4 <- dmT, XQ2 <- xdtT)
    prep_transpose<<<dim3(D_INNER / 64, ROWS / 64), 256, 0, stream>>>(
        ws + OFF_DMOD, ws + OFF_XS, ws + OFF_XQ4, ws + OFF_XQ2);
    // 10b. chunked scan + gate (v4)
    scan_chunked<<<Bb * D_INNER, 512, 0, stream>>>(
        ws + OFF_XQ4, ws + OFF_XQ2, ws + OFF_PROJ, ws + OFF_XZ, base, shifts, ws + OFF_YG);
    // 11. quant for out_proj (bf16)
    rowmax_quant_bf16<<<ROWS, 256, 0, stream>>>(ws + OFF_YG, D_INNER,
                                                ws + OFF_SW + 3, xq4, ws + OFF_S4);
    // 12. out_proj MFMA GEMM + residual epilogue -> d_out (384 blocks)
    gemm_mfma<2, 2><<<dim3(D_MODEL / 64, ROWS / 64), 256, 0, stream>>>(
        xq4, wqout, ws + OFF_S4, out,
        ROWS, D_MODEL, D_INNER, hs, rg);
}

// Round 5
// 282.820 us; speedup vs baseline: 7.9906x; 1.2107x over previous
//
#include <hip/hip_runtime.h>
#include <hip/hip_bf16.h>
#include <math.h>

// ---------------- problem constants ----------------
#define D_MODEL 768
#define D_STATE 16
#define DT_RANK 48
#define D_INNER 1536           // 2*D_MODEL
#define XZ_DIM  3072           // 2*D_INNER
#define PROJ_DIM 80            // DT_RANK + 2*D_STATE
#define Bb 2
#define Ll 1024
#define ROWS (Bb*Ll)           // 2048

// ---------------- ws layout (float offsets; bf16 buffers reuse same regions) ----------------
#define OFF_PART   0u                     // 128 partials
#define OFF_SW     256u                   // 4 scalars
#define OFF_WQIN   512u                   // bf16 [3072][768]
#define OFF_WQXPT  (OFF_WQIN  + 2359296u) // f32 [1536][80] (transposed)
#define OFF_WQDT   (OFF_WQXPT + 122880u)  // f32 [1536][48]
#define OFF_WQOUT  (OFF_WQDT  + 73728u)   // bf16 [768][1536]
#define OFF_XQ1    (OFF_WQOUT + 1179648u) // bf16 [2048][768]
#define OFF_S1     (OFF_XQ1   + 1572864u) // 2048
#define OFF_XZ     (OFF_S1    + 2048u)    // f32 [2048][3072]
#define OFF_XS     (OFF_XZ    + 6291456u) // f32 [2048][1536]
#define OFF_XQ2    (OFF_XS    + 3145728u) // f32 2048x1536 (later reused as xdtT [1536][2][1024])
#define OFF_S2     (OFF_XQ2   + 3145728u) // 2048
#define OFF_PROJ   (OFF_S2    + 2048u)    // 2048x80
#define OFF_XQ3    (OFF_PROJ  + 163840u)  // f32 [2048][48]
#define OFF_S3     (OFF_XQ3   + 98304u)   // 2048
#define OFF_DMOD   (OFF_S3    + 2048u)    // (unused now)
#define OFF_YG     (OFF_DMOD  + 3145728u) // f32 [2048][1536]
#define OFF_XQ4    (OFF_YG    + 3145728u) // dmT f32 [1536][2][1024], then bf16 [2048][1536]
#define OFF_S4     (OFF_XQ4   + 3145728u) // 2048

typedef short sh8 __attribute__((ext_vector_type(8)));
typedef float f32x4 __attribute__((ext_vector_type(4)));

#define N_IN_W  (XZ_DIM * D_MODEL)     // 2359296
#define N_XP_W  (PROJ_DIM * D_INNER)   // 122880
#define N_DT_W  (D_INNER * DT_RANK)    // 73728
#define N_OUT_W (D_MODEL * D_INNER)    // 1179648

// ---------------- helpers ----------------
__device__ __forceinline__ float blk_sum(float v, float* sm) {
    int tid = threadIdx.x;
    #pragma unroll
    for (int off = 32; off; off >>= 1) v += __shfl_down(v, off);
    __syncthreads();
    if ((tid & 63) == 0) sm[tid >> 6] = v;
    __syncthreads();
    return (sm[0] + sm[1]) + (sm[2] + sm[3]);
}
__device__ __forceinline__ float blk_max(float v, float* sm) {
    int tid = threadIdx.x;
    #pragma unroll
    for (int off = 32; off; off >>= 1) v = fmaxf(v, __shfl_down(v, off));
    __syncthreads();
    if ((tid & 63) == 0) sm[tid >> 6] = v;
    __syncthreads();
    return fmaxf(fmaxf(sm[0], sm[1]), fmaxf(sm[2], sm[3]));
}
__device__ __forceinline__ float clampf(float v, float lo, float hi) {
    return fminf(fmaxf(v, lo), hi);
}
__device__ __forceinline__ void gload_lds16(const __hip_bfloat16* g, __hip_bfloat16* l) {
    __builtin_amdgcn_global_load_lds(
        (const __attribute__((address_space(1))) void*)g,
        (__attribute__((address_space(3))) void*)l, 16, 0, 0);
}

// ---------------- weight absmean: all 4 matrices in one launch ----------------
__global__ void absmean_all(const float* __restrict__ w0, const float* __restrict__ w1,
                            const float* __restrict__ w2, const float* __restrict__ w3,
                            float* __restrict__ part) {
    __shared__ float sm[4];
    int bid = blockIdx.x;
    const float* w; int n, sub, nb;
    if (bid < 64)      { w = w0; n = N_IN_W;  sub = bid;      nb = 64; }
    else if (bid < 80) { w = w1; n = N_XP_W;  sub = bid - 64; nb = 16; }
    else if (bid < 96) { w = w2; n = N_DT_W;  sub = bid - 80; nb = 16; }
    else               { w = w3; n = N_OUT_W; sub = bid - 96; nb = 32; }
    float sum = 0.f;
    for (int i = sub * 256 + threadIdx.x; i < n; i += nb * 256)
        sum += fabsf(w[i]);
    sum = blk_sum(sum, sm);
    if (threadIdx.x == 0) part[bid] = sum;
}

__global__ void absmean_final4(const float* __restrict__ part, float* __restrict__ sw) {
    int tid = threadIdx.x;  // 64 threads
    const int cnt[4] = {64, 16, 16, 32};
    const int off[4] = {0, 64, 80, 96};
    const int ns[4]  = {N_IN_W, N_XP_W, N_DT_W, N_OUT_W};
    #pragma unroll
    for (int m = 0; m < 4; ++m) {
        float v = (tid < cnt[m]) ? part[off[m] + tid] : 0.f;
        #pragma unroll
        for (int o = 32; o; o >>= 1) v += __shfl_down(v, o);
        if (tid == 0) sw[m] = v / (float)ns[m] + 1e-6f;
    }
}

// ---------------- all 4 weight quantizations in one launch ----------------
__global__ void quant_all(const float* __restrict__ w_in, const float* __restrict__ w_xp,
                          const float* __restrict__ w_dt, const float* __restrict__ w_out,
                          const float* __restrict__ sw,
                          __hip_bfloat16* __restrict__ wqin, float* __restrict__ wqxpT,
                          float* __restrict__ wqdt, __hip_bfloat16* __restrict__ wqout) {
    int idx = blockIdx.x * 256 + threadIdx.x;
    if (idx < N_IN_W) {
        float v = rintf(clampf(w_in[idx] / sw[0], -1.f, 1.f));
        wqin[idx] = __float2bfloat16(v);
    } else if (idx < N_IN_W + N_XP_W) {
        int i = idx - N_IN_W;
        int j = i / D_INNER, k = i % D_INNER;
        wqxpT[k * PROJ_DIM + j] = rintf(clampf(w_xp[i] / sw[1], -1.f, 1.f));
    } else if (idx < N_IN_W + N_XP_W + N_DT_W) {
        int i = idx - N_IN_W - N_XP_W;
        wqdt[i] = rintf(clampf(w_dt[i] / sw[2], -1.f, 1.f));
    } else if (idx < N_IN_W + N_XP_W + N_DT_W + N_OUT_W) {
        int i = idx - N_IN_W - N_XP_W - N_DT_W;
        float v = rintf(clampf(w_out[i] / sw[3], -1.f, 1.f));
        wqout[i] = __float2bfloat16(v);
    }
}

// ---------------- fused center x2 + bitshift-norm + act quant (bf16 out) ----------------
__global__ __launch_bounds__(256) void norm_quant(
    const float* __restrict__ x, const float* __restrict__ gamma,
    const float* __restrict__ swp, __hip_bfloat16* __restrict__ xq, float* __restrict__ s1) {
    int row = blockIdx.x, tid = threadIdx.x;
    const float* xr = x + (size_t)row * D_MODEL;
    __shared__ float sm[4];
    float v0 = xr[tid], v1 = xr[tid + 256], v2 = xr[tid + 512];
    float m1 = blk_sum(v0 + v1 + v2, sm) * (1.f / D_MODEL);
    v0 -= m1; v1 -= m1; v2 -= m1;
    float m2 = blk_sum(v0 + v1 + v2, sm) * (1.f / D_MODEL);
    v0 -= m2; v1 -= m2; v2 -= m2;
    float var = blk_sum(v0 * v0 + v1 * v1 + v2 * v2, sm) * (1.f / D_MODEL);
    float rms = sqrtf(var + 1e-6f);
    float k = fmaxf(rintf(log2f(rms)), 0.f);
    float inv = exp2f(-k);
    float g0 = gamma[tid], g1 = gamma[tid + 256], g2 = gamma[tid + 512];
    float h0 = v0 * inv * g0, h1 = v1 * inv * g1, h2 = v2 * inv * g2;
    float mx = blk_max(fmaxf(fabsf(h0), fmaxf(fabsf(h1), fabsf(h2))), sm);
    float sx = 127.f / (mx + 1e-6f);
    __hip_bfloat16* xo = xq + (size_t)row * D_MODEL;
    xo[tid]       = __float2bfloat16(rintf(clampf(h0 * sx, -128.f, 127.f)));
    xo[tid + 256] = __float2bfloat16(rintf(clampf(h1 * sx, -128.f, 127.f)));
    xo[tid + 512] = __float2bfloat16(rintf(clampf(h2 * sx, -128.f, 127.f)));
    if (tid == 0) s1[row] = swp[0] * (mx + 1e-6f) / 127.f;
}

// ---------------- row-wise |max| + act quant (bf16 out) ----------------
__global__ void rowmax_quant_bf16(const float* __restrict__ in, int K,
                                  const float* __restrict__ swp,
                                  __hip_bfloat16* __restrict__ xq, float* __restrict__ sout) {
    int row = blockIdx.x, tid = threadIdx.x;
    const float* ir = in + (size_t)row * K;
    __shared__ float sm[4];
    float mx = 0.f;
    for (int k = tid; k < K; k += 256) mx = fmaxf(mx, fabsf(ir[k]));
    mx = blk_max(mx, sm);
    float sx = 127.f / (mx + 1e-6f);
    for (int k = tid; k < K; k += 256)
        xq[(size_t)row * K + k] = __float2bfloat16(rintf(clampf(ir[k] * sx, -128.f, 127.f)));
    if (tid == 0) sout[row] = swp[0] * (mx + 1e-6f) / 127.f;
}

// ---------------- MFMA bf16 GEMM: C[M,N] = (A[M,K] @ W[N,K]^T) * s[row] (+resid) ----------------
template<int MF, int NF>
__global__ __launch_bounds__(256) void gemm_mfma(
    const __hip_bfloat16* __restrict__ A, const __hip_bfloat16* __restrict__ W,
    const float* __restrict__ s, float* __restrict__ C,
    int M, int N, int K,
    const float* __restrict__ resid, const float* __restrict__ rg) {
    constexpr int BM = MF * 32, BN = NF * 32;
    __shared__ __hip_bfloat16 smA[BM * 32];
    __shared__ __hip_bfloat16 smB[BN * 32];
    const int tid = threadIdx.x;
    const int w = tid >> 6, lane = tid & 63;
    const int bm = blockIdx.y * BM, bn = blockIdx.x * BN;
    const int wr = (w >> 1) * (MF * 16), wc = (w & 1) * (NF * 16);
    const int fr = lane & 15, fq = lane >> 4;
    const int srow = lane >> 2;
    const int scol = (lane & 3) * 8;

    f32x4 acc[MF][NF];
    #pragma unroll
    for (int i = 0; i < MF; ++i)
        #pragma unroll
        for (int j = 0; j < NF; ++j)
            acc[i][j] = (f32x4){0.f, 0.f, 0.f, 0.f};

    for (int k0 = 0; k0 < K; k0 += 32) {
        #pragma unroll
        for (int q = 0; q < BM / 64; ++q) {
            int rr = (w * (BM / 64) + q) * 16;
            gload_lds16(A + (size_t)(bm + rr + srow) * K + k0 + scol, &smA[rr * 32]);
        }
        #pragma unroll
        for (int q = 0; q < BN / 64; ++q) {
            int rr = (w * (BN / 64) + q) * 16;
            gload_lds16(W + (size_t)(bn + rr + srow) * K + k0 + scol, &smB[rr * 32]);
        }
        __syncthreads();
        sh8 af[MF], bfr[NF];
        #pragma unroll
        for (int i = 0; i < MF; ++i)
            af[i] = *(const sh8*)&smA[(wr + i * 16 + fr) * 32 + fq * 8];
        #pragma unroll
        for (int j = 0; j < NF; ++j)
            bfr[j] = *(const sh8*)&smB[(wc + j * 16 + fr) * 32 + fq * 8];
        #pragma unroll
        for (int i = 0; i < MF; ++i)
            #pragma unroll
            for (int j = 0; j < NF; ++j)
                acc[i][j] = __builtin_amdgcn_mfma_f32_16x16x32_bf16(af[i], bfr[j], acc[i][j], 0, 0, 0);
        __syncthreads();
    }
    const float rgv = resid ? rg[0] : 0.f;
    #pragma unroll
    for (int i = 0; i < MF; ++i) {
        #pragma unroll
        for (int q = 0; q < 4; ++q) {
            int r = bm + wr + i * 16 + fq * 4 + q;
            float sc = s[r];
            #pragma unroll
            for (int j = 0; j < NF; ++j) {
                int col = bn + wc + j * 16 + fr;
                float v = acc[i][j][q] * sc;
                size_t o = (size_t)r * N + col;
                if (resid) v = resid[o] + v * rgv;
                C[o] = v;
            }
        }
    }
}

// ---------------- fused depthwise conv(4)+softplus + rowmax + quant ----------------
__global__ __launch_bounds__(256) void conv_quant(
    const float* __restrict__ xz, const float* __restrict__ cw, const float* __restrict__ cb,
    const float* __restrict__ swp, float* __restrict__ xs,
    float* __restrict__ xq2, float* __restrict__ s2) {
    int row = blockIdx.x, tid = threadIdx.x;
    int b = row >> 10, l = row & 1023;
    __shared__ float sm[4];
    float v[6];
    #pragma unroll
    for (int k = 0; k < 6; ++k) {
        int c = tid + k * 256;
        float acc = cb[c];
        #pragma unroll
        for (int t = 0; t < 4; ++t) {
            int tt = l - 3 + t;
            if (tt >= 0)
                acc = fmaf(cw[c * 4 + t], xz[(size_t)(b * Ll + tt) * XZ_DIM + c], acc);
        }
        acc = clampf(acc, -50.f, 50.f);
        v[k] = 0.5f * (acc + sqrtf(fmaf(acc, acc, 4.f)));
    }
    float mx = 0.f;
    #pragma unroll
    for (int k = 0; k < 6; ++k) mx = fmaxf(mx, fabsf(v[k]));
    mx = blk_max(mx, sm);
    float sx = 127.f / (mx + 1e-6f);
    #pragma unroll
    for (int k = 0; k < 6; ++k) {
        int c = tid + k * 256;
        xs[(size_t)row * D_INNER + c] = v[k];
        xq2[(size_t)row * D_INNER + c] = rintf(clampf(v[k] * sx, -128.f, 127.f));
    }
    if (tid == 0) s2[row] = swp[0] * (mx + 1e-6f) / 127.f;
}

// ---------------- x_proj GEMM + fused dt-quant epilogue ----------------
// proj[2048,80] = (xq2 @ wqT) * s2; then dt-quant over cols 0..47 (same row/block).
__global__ __launch_bounds__(256) void gemm_row80_dtq(
    const float* __restrict__ xq, const float* __restrict__ wT,
    const float* __restrict__ s, const float* __restrict__ swp,
    float* __restrict__ proj, float* __restrict__ xq3, float* __restrict__ s3) {
    int row = blockIdx.x, tid = threadIdx.x;
    __shared__ float a[D_INNER];
    __shared__ float psum[3][PROJ_DIM];
    for (int k = tid; k < D_INNER; k += 256) a[k] = xq[(size_t)row * D_INNER + k];
    __syncthreads();
    if (tid < 240) {
        int col = tid % PROJ_DIM, slice = tid / PROJ_DIM;
        int k0 = slice * 512, k1 = k0 + 512;
        float acc = 0.f;
        for (int k = k0; k < k1; ++k)
            acc = fmaf(a[k], wT[k * PROJ_DIM + col], acc);
        psum[slice][col] = acc;
    }
    __syncthreads();
    float pv = 0.f;
    if (tid < PROJ_DIM) {
        pv = (psum[0][tid] + psum[1][tid] + psum[2][tid]) * s[row];
        proj[row * PROJ_DIM + tid] = pv;
    }
    // dt-quant: max |proj[0..47]| — all inside wave 0
    if (tid < 64) {
        float av = (tid < DT_RANK) ? fabsf(pv) : 0.f;
        #pragma unroll
        for (int o = 32; o; o >>= 1) av = fmaxf(av, __shfl_down(av, o));
        float mx = __shfl(av, 0);
        float sx = 127.f / (mx + 1e-6f);
        if (tid < DT_RANK)
            xq3[row * DT_RANK + tid] = rintf(clampf(pv * sx, -128.f, 127.f));
        if (tid == 0) s3[row] = swp[0] * (mx + 1e-6f) / 127.f;
    }
}

// ---------------- dt_proj GEMM (K=48, VALU) + fused dtv/xdt + transpose ----------------
// computes dmod tile [64 l][64 d] in registers, then writes dmT/xdtT in [d][b][l] layout.
__global__ __launch_bounds__(256) void gemm_dt_fused(
    const float* __restrict__ A, const float* __restrict__ W,
    const float* __restrict__ s, const float* __restrict__ xs,
    float* __restrict__ dmT, float* __restrict__ xdtT) {
    __shared__ float As[16][68];
    __shared__ float Ws[16][68];
    __shared__ float t0[64][65];
    __shared__ float t1[64][65];
    int bm = blockIdx.y * 64, bn = blockIdx.x * 64;
    int tid = threadIdx.x;
    int tx = tid & 15, ty = tid >> 4;
    float acc[4][4] = {};
    for (int k0 = 0; k0 < DT_RANK; k0 += 16) {
        int idx = tid;
        #pragma unroll
        for (int u = 0; u < 4; ++u, idx += 256) {
            int r = idx >> 4, c = idx & 15;
            As[c][r] = A[(size_t)(bm + r) * DT_RANK + k0 + c];
            Ws[c][r] = W[(size_t)(bn + r) * DT_RANK + k0 + c];
        }
        __syncthreads();
        #pragma unroll
        for (int kk = 0; kk < 16; ++kk) {
            float a0 = As[kk][ty * 4 + 0], a1 = As[kk][ty * 4 + 1];
            float a2 = As[kk][ty * 4 + 2], a3 = As[kk][ty * 4 + 3];
            float w0 = Ws[kk][tx * 4 + 0], w1 = Ws[kk][tx * 4 + 1];
            float w2 = Ws[kk][tx * 4 + 2], w3 = Ws[kk][tx * 4 + 3];
            acc[0][0] = fmaf(a0, w0, acc[0][0]); acc[0][1] = fmaf(a0, w1, acc[0][1]);
            acc[0][2] = fmaf(a0, w2, acc[0][2]); acc[0][3] = fmaf(a0, w3, acc[0][3]);
            acc[1][0] = fmaf(a1, w0, acc[1][0]); acc[1][1] = fmaf(a1, w1, acc[1][1]);
            acc[1][2] = fmaf(a1, w2, acc[1][2]); acc[1][3] = fmaf(a1, w3, acc[1][3]);
            acc[2][0] = fmaf(a2, w0, acc[2][0]); acc[2][1] = fmaf(a2, w1, acc[2][1]);
            acc[2][2] = fmaf(a2, w2, acc[2][2]); acc[2][3] = fmaf(a2, w3, acc[2][3]);
            acc[3][0] = fmaf(a3, w0, acc[3][0]); acc[3][1] = fmaf(a3, w1, acc[3][1]);
            acc[3][2] = fmaf(a3, w2, acc[3][2]); acc[3][3] = fmaf(a3, w3, acc[3][3]);
        }
        __syncthreads();
    }
    // dmod tile -> t0 (transposed store: [d-in-tile][l-in-tile])
    int row0 = bm + ty * 4, col0 = bn + tx * 4;
    #pragma unroll
    for (int i = 0; i < 4; ++i) {
        float sc = s[row0 + i];
        #pragma unroll
        for (int j = 0; j < 4; ++j)
            t0[tx * 4 + j][ty * 4 + i] = acc[i][j] * sc;
    }
    // xs tile -> t1 (coalesced read, transposed store)
    #pragma unroll
    for (int it = 0; it < 16; ++it) {
        int idx = tid + it * 256;
        int rr = idx >> 6, cc = idx & 63;
        t1[cc][rr] = xs[(size_t)(bm + rr) * D_INNER + bn + cc];
    }
    __syncthreads();
    int b = bm >> 10, lbase = bm & 1023;
    #pragma unroll
    for (int it = 0; it < 16; ++it) {
        int idx = tid + it * 256;
        int dd = idx >> 6, ll = idx & 63;
        float dm = t0[dd][ll];
        float xv = t1[dd][ll];
        float dtv = clampf(0.5f * (dm + sqrtf(fmaf(dm, dm, 4.f))) * 0.01f, 0.f, 0.1f);
        size_t dst = ((size_t)(bn + dd) * Bb + b) * Ll + lbase + ll;
        dmT[dst]  = dm;
        xdtT[dst] = xv * dtv;
    }
}

// ---------------- chunked parallel scan + C-contraction + z gate ----------------
// R3 recompute structure (VGPR-light) + padded LDS (conflict-free chunk reads).
#define NCHUNK 32
#define CLEN   32
#define PADIDX(i) ((i) + ((i) >> 5))
__global__ __launch_bounds__(512) void scan_chunked(
    const float* __restrict__ dmT, const float* __restrict__ xdtT,
    const float* __restrict__ proj, const float* __restrict__ xz,
    const float* __restrict__ base, const float* __restrict__ shifts,
    float* __restrict__ yg) {
    int bid = blockIdx.x;          // 0..Bb*D_INNER-1
    int d = bid >> 1, b = bid & 1;
    int tid = threadIdx.x;
    int chunk = tid >> 4, n = tid & 15;
    __shared__ float dmL[Ll + Ll / 32];
    __shared__ float xdtL[Ll + Ll / 32];
    __shared__ float Ps[NCHUNK][16];
    __shared__ float Hs[NCHUNK][16];
    __shared__ float Cin[NCHUNK][16];
    size_t tbase = (size_t)bid * Ll;
    for (int i = tid; i < Ll; i += 512) {
        dmL[PADIDX(i)]  = dmT[tbase + i];
        xdtL[PADIDX(i)] = xdtT[tbase + i];
    }
    float bs_n  = base[d * D_STATE + n];
    float asc_n = exp2f(-shifts[d * D_STATE + n]);
    __syncthreads();
    // pass A: local scan from 0, record (prod a, h_end)
    float P = 1.f, h = 0.f;
    int l0 = chunk * CLEN;
    int pbase = PADIDX(l0);   // contiguous within chunk (CLEN==32)
    const float* projR = proj + (size_t)(b * Ll) * PROJ_DIM;
    for (int s = 0; s < CLEN; ++s) {
        float dm = dmL[pbase + s], xdt = xdtL[pbase + s];
        float Bv = projR[(size_t)(l0 + s) * PROJ_DIM + DT_RANK + n];
        float u = clampf(xdt * Bv, -100.f, 100.f);
        float a = clampf(bs_n + dm, 0.f, 32000.f) * asc_n;
        h = fmaf(a, h, u);
        P *= a;
    }
    Ps[chunk][n] = P;
    Hs[chunk][n] = h;
    __syncthreads();
    // mid-scan over chunk summaries (serial, 16 threads)
    if (tid < 16) {
        float carry = 0.f;
        for (int c = 0; c < NCHUNK; ++c) {
            Cin[c][tid] = carry;
            carry = fmaf(Ps[c][tid], carry, Hs[c][tid]);
        }
    }
    __syncthreads();
    // pass C: re-scan with carry-in, fused y = sum_n clip(h)*C, gate, store
    h = Cin[chunk][n];
    for (int s = 0; s < CLEN; ++s) {
        int l = l0 + s;
        float dm = dmL[pbase + s], xdt = xdtL[pbase + s];
        size_t pr = (size_t)l * PROJ_DIM;
        float Bv = projR[pr + DT_RANK + n];
        float Cv = projR[pr + DT_RANK + D_STATE + n];
        float u = clampf(xdt * Bv, -100.f, 100.f);
        float a = clampf(bs_n + dm, 0.f, 32000.f) * asc_n;
        h = fmaf(a, h, u);
        float hc = clampf(h, -1000.f, 1000.f);
        float y = hc * Cv;
        y += __shfl_xor(y, 1);
        y += __shfl_xor(y, 2);
        y += __shfl_xor(y, 4);
        y += __shfl_xor(y, 8);
        if (n == 0) {
            size_t r = (size_t)b * Ll + l;
            float z = xz[r * XZ_DIM + D_INNER + d];
            float g = 0.5f * (z / sqrtf(fmaf(z, z, 1.f)) + 1.f);
            yg[r * D_INNER + d] = y * g;
        }
    }
}

// ---------------- launcher ----------------
extern "C" void kernel_launch(void* const* d_in, const int* in_sizes, int n_in,
                              void* d_out, int out_size, void* d_ws, size_t ws_size,
                              hipStream_t stream) {
    const float* hs    = (const float*)d_in[0];
    const float* gamma = (const float*)d_in[1];
    const float* w_in  = (const float*)d_in[2];
    const float* cw    = (const float*)d_in[3];
    const float* cb    = (const float*)d_in[4];
    const float* w_xp  = (const float*)d_in[5];
    const float* w_dt  = (const float*)d_in[6];
    const float* w_out = (const float*)d_in[7];
    const float* base  = (const float*)d_in[8];
    const float* rg    = (const float*)d_in[9];
    const float* shifts= (const float*)d_in[10];
    float* ws  = (float*)d_ws;
    float* out = (float*)d_out;

    __hip_bfloat16* wqin  = (__hip_bfloat16*)(ws + OFF_WQIN);
    __hip_bfloat16* wqout = (__hip_bfloat16*)(ws + OFF_WQOUT);
    __hip_bfloat16* xq1   = (__hip_bfloat16*)(ws + OFF_XQ1);
    __hip_bfloat16* xq4   = (__hip_bfloat16*)(ws + OFF_XQ4);

    // 1. weight scales
    absmean_all<<<128, 256, 0, stream>>>(w_in, w_xp, w_dt, w_out, ws + OFF_PART);
    absmean_final4<<<1, 64, 0, stream>>>(ws + OFF_PART, ws + OFF_SW);
    // 2. ternary weights
    const int n_tot = N_IN_W + N_XP_W + N_DT_W + N_OUT_W;
    quant_all<<<(n_tot + 255) / 256, 256, 0, stream>>>(
        w_in, w_xp, w_dt, w_out, ws + OFF_SW,
        wqin, ws + OFF_WQXPT, ws + OFF_WQDT, wqout);
    // 3. norm + act quant (bf16)
    norm_quant<<<ROWS, 256, 0, stream>>>(hs, gamma, ws + OFF_SW + 0, xq1, ws + OFF_S1);
    // 4. in_proj MFMA GEMM -> xz
    gemm_mfma<4, 4><<<dim3(XZ_DIM / 128, ROWS / 128), 256, 0, stream>>>(
        xq1, wqin, ws + OFF_S1, ws + OFF_XZ,
        ROWS, XZ_DIM, D_MODEL, nullptr, nullptr);
    // 5+6. fused conv + softplus + rowmax + quant
    conv_quant<<<ROWS, 256, 0, stream>>>(ws + OFF_XZ, cw, cb, ws + OFF_SW + 1,
                                         ws + OFF_XS, ws + OFF_XQ2, ws + OFF_S2);
    // 7+8. x_proj GEMM + fused dt-quant
    gemm_row80_dtq<<<ROWS, 256, 0, stream>>>(ws + OFF_XQ2, ws + OFF_WQXPT, ws + OFF_S2,
                                             ws + OFF_SW + 2,
                                             ws + OFF_PROJ, ws + OFF_XQ3, ws + OFF_S3);
    // 9+10a. dt_proj GEMM + fused dtv/xdt/transpose (XQ4 <- dmT, XQ2 <- xdtT)
    gemm_dt_fused<<<dim3(D_INNER / 64, ROWS / 64), 256, 0, stream>>>(
        ws + OFF_XQ3, ws + OFF_WQDT, ws + OFF_S3, ws + OFF_XS,
        ws + OFF_XQ4, ws + OFF_XQ2);
    // 10b. chunked scan + gate
    scan_chunked<<<Bb * D_INNER, 512, 0, stream>>>(
        ws + OFF_XQ4, ws + OFF_XQ2, ws + OFF_PROJ, ws + OFF_XZ, base, shifts, ws + OFF_YG);
    // 11. quant for out_proj (bf16)
    rowmax_quant_bf16<<<ROWS, 256, 0, stream>>>(ws + OFF_YG, D_INNER,
                                                ws + OFF_SW + 3, xq4, ws + OFF_S4);
    // 12. out_proj MFMA GEMM + residual epilogue -> d_out
    gemm_mfma<2, 2><<<dim3(D_MODEL / 64, ROWS / 64), 256, 0, stream>>>(
        xq4, wqout, ws + OFF_S4, out,
        ROWS, D_MODEL, D_INNER, hs, rg);
}